// Round 1
// 383.372 us; speedup vs baseline: 1.0507x; 1.0507x over previous
//
#include <hip/hip_runtime.h>
#include <math.h>

#define B_   4096

typedef __attribute__((ext_vector_type(8)))  short bf16x8;   // 8 bf16 = 4 VGPR
typedef __attribute__((ext_vector_type(4)))  float f32x4;
typedef __attribute__((ext_vector_type(16))) float f32x16;

// packed f32->bf16 RNE, single VALU instruction (gfx950; no builtin — T12 recipe)
__device__ __forceinline__ unsigned int pk2(float a, float b) {
    unsigned int r;
    asm("v_cvt_pk_bf16_f32 %0, %1, %2" : "=v"(r) : "v"(a), "v"(b));
    return r;
}
__device__ __forceinline__ f32x16 zero16() {
    f32x16 z;
    #pragma unroll
    for (int i = 0; i < 16; ++i) z[i] = 0.f;
    return z;
}
// quad all-reduce max via DPP (VALU only, no LDS pipe). All lanes active.
// Kept as builtins (not inline-asm v_max_f32_dpp): LLVM's hazard recognizer
// does not see inline asm as DPP, so asm DPP risks missing wait-states.
__device__ __forceinline__ float maxq(float v) {
    int y1 = __builtin_amdgcn_update_dpp(0, __float_as_int(v), 0xB1, 0xF, 0xF, true); // xor1
    float v1 = fmaxf(v, __int_as_float(y1));
    int y2 = __builtin_amdgcn_update_dpp(0, __float_as_int(v1), 0x4E, 0xF, 0xF, true); // xor2
    return fmaxf(v1, __int_as_float(y2));
}

// ---------------------------------------------------------------------------
// prep: all MFMA A-fragments (26 x 64 lanes x 16B). Bias folded at k=15 for
// the 32x32x16 conv fragments (B supplies a ones-column there).
//  e 0..19 : phys phase-2 (16x16x32), e=(kk*2+Ks)*2+ftile
//  e 20..23: encoder conv (32x32x16), e-20=enc*2+mt; j<9 W, j==15 bias
//  e 24..25: phys phase-1 (32x32x16), mt=e-24;       j<15 W, j==15 bias
// ---------------------------------------------------------------------------
__global__ void prep_frags(const float* __restrict__ W2,
                           const float* __restrict__ Wc_v,
                           const float* __restrict__ Wc_p,
                           const float* __restrict__ W1,
                           const float* __restrict__ bc_v,
                           const float* __restrict__ bc_p,
                           const float* __restrict__ b1,
                           unsigned short* __restrict__ ws_frag)
{
    int gid = blockIdx.x * 256 + threadIdx.x;
    if (gid >= 26 * 64) return;
    int lane = gid & 63, e = gid >> 6;
    unsigned int w[4];
    if (e < 20) {
        int ft = e & 1, Ks = (e >> 1) & 1, kk = e >> 2;
        int m = lane & 15, kg = lane >> 4;
        int f = ft * 16 + m;
        #pragma unroll
        for (int p = 0; p < 4; ++p) {
            int i0 = Ks * 32 + kg * 8 + 2 * p;
            float v0 = (f < 30) ? W2[f * 320 + i0 * 5 + kk] : 0.f;
            float v1 = (f < 30) ? W2[f * 320 + (i0 + 1) * 5 + kk] : 0.f;
            w[p] = pk2(v0, v1);
        }
    } else if (e < 24) {
        int e2 = e - 20, enc = e2 >> 1, mt = e2 & 1;
        const float* Wc = enc ? Wc_p : Wc_v;
        const float* bc = enc ? bc_p : bc_v;
        int c = mt * 32 + (lane & 31), kg = lane >> 5;
        #pragma unroll
        for (int p = 0; p < 4; ++p) {
            int j0 = kg * 8 + 2 * p, j1 = j0 + 1;
            float v0 = (j0 < 9) ? Wc[c * 9 + (j0 % 3) * 3 + (j0 / 3)] : 0.f;
            float v1 = (j1 < 9) ? Wc[c * 9 + (j1 % 3) * 3 + (j1 / 3)]
                                : (j1 == 15 ? bc[c] : 0.f);
            w[p] = pk2(v0, v1);
        }
    } else {
        int mt = e - 24;
        int c = mt * 32 + (lane & 31), kg = lane >> 5;
        #pragma unroll
        for (int p = 0; p < 4; ++p) {
            int j0 = kg * 8 + 2 * p, j1 = j0 + 1;
            float v0 = (j0 < 15) ? W1[c * 15 + (j0 % 3) * 5 + (j0 / 3)] : 0.f;
            float v1 = (j1 < 15) ? W1[c * 15 + (j1 % 3) * 5 + (j1 / 3)]
                                 : (j1 == 15 ? b1[c] : 0.f);
            w[p] = pk2(v0, v1);
        }
    }
    ((uint4*)ws_frag)[gid] = make_uint4(w[0], w[1], w[2], w[3]);
}

// ---------------------------------------------------------------------------
// Encoder: conv(3->64,K=3)+bias (in-K) + ReLU + mean, all via 32x32x16 MFMA.
// B built per-lane straight from global (VMEM pipe; no LDS staging at all).
// Lane-sum via one LDS transpose (hmat) instead of shuffle butterflies.
// ---------------------------------------------------------------------------
__global__ __launch_bounds__(256, 4) void encode_mfma_kernel(
    const float* __restrict__ S_V, const float* __restrict__ S_P,
    const unsigned short* __restrict__ Frag,
    float* __restrict__ hv, float* __restrict__ hp)
{
    __shared__ __align__(16) float hmat[4 * 32 * 68];   // 34.8 KB
    const int enc = blockIdx.y;
    const float* __restrict__ S = enc ? S_P : S_V;
    float* hout = enc ? hp : hv;
    const int b = blockIdx.x, tid = threadIdx.x;
    const int lane = tid & 63, wv = tid >> 6;
    const int n = lane & 31, kg = lane >> 5;
    const float* __restrict__ xb = S + (size_t)b * 3072;

    const bf16x8* fr = (const bf16x8*)Frag;
    bf16x8 Af0 = fr[(20 + enc * 2) * 64 + lane];
    bf16x8 Af1 = fr[(21 + enc * 2) * 64 + lane];

    float h0[16], h1[16];
    #pragma unroll
    for (int r = 0; r < 16; ++r) { h0[r] = 0.f; h1[r] = 0.f; }

    #pragma unroll 1
    for (int nt = wv; nt < 32; nt += 4) {
        const int t = nt * 32 + n;
        union { unsigned int u[4]; bf16x8 v; } bb;
        bb.u[0] = bb.u[1] = bb.u[2] = bb.u[3] = 0u;
        if (t < 1022) {
            const float* xp = xb + 3 * t;
            if (kg == 0) {          // k=0..7 -> x[3t..3t+7]
                bb.u[0] = pk2(xp[0], xp[1]); bb.u[1] = pk2(xp[2], xp[3]);
                bb.u[2] = pk2(xp[4], xp[5]); bb.u[3] = pk2(xp[6], xp[7]);
            } else {                // k=8 -> x[3t+8]; k=15 -> 1.0 (bias col)
                bb.u[0] = pk2(xp[8], 0.f);
                bb.u[3] = 0x3F800000u;   // packed (0.0, 1.0) in bf16
            }
        }
        f32x16 z = zero16();
        f32x16 y0 = __builtin_amdgcn_mfma_f32_32x32x16_bf16(Af0, bb.v, z, 0, 0, 0);
        f32x16 y1 = __builtin_amdgcn_mfma_f32_32x32x16_bf16(Af1, bb.v, z, 0, 0, 0);
        #pragma unroll
        for (int r = 0; r < 16; ++r) {
            h0[r] += fmaxf(y0[r], 0.f);
            h1[r] += fmaxf(y1[r], 0.f);
        }
    }

    // transpose to LDS: c = (r&3) + 8*(r>>2) + 4*kg  (+32 for h1)
    float* hm = hmat + (wv * 32 + n) * 68;
    #pragma unroll
    for (int g4 = 0; g4 < 4; ++g4) {
        int c0 = g4 * 8 + 4 * kg;
        *(float4*)(hm + c0)      = make_float4(h0[4*g4+0], h0[4*g4+1], h0[4*g4+2], h0[4*g4+3]);
        *(float4*)(hm + c0 + 32) = make_float4(h1[4*g4+0], h1[4*g4+1], h1[4*g4+2], h1[4*g4+3]);
    }
    __syncthreads();
    if (tid < 64) {                 // lane = channel c; 2-way banks (free)
        float s = 0.f;
        #pragma unroll 8
        for (int gn = 0; gn < 128; ++gn) s += hmat[gn * 68 + tid];
        hout[(size_t)b * 64 + tid] = s * (1.0f / 1022.0f);
    }
}

// ---------------------------------------------------------------------------
// Physical model. Phase 1: conv(3->64,K=5)+bias(in-K) via 32x32x16 MFMA with
// per-lane global B; maxpool4 via DPP quad-max; survivors write bf16 p1T.
// Phase 2: 5 shifted 16x16x32 GEMMs over p1T (Ks-outer: 10 live A-frags).
// Epilogue: DPP quad-max pool -> ymat (overlaid on dead p1T) -> strided sum.
// ---------------------------------------------------------------------------
#define P1TS 72
__global__ __launch_bounds__(256, 4) void phys_kernel(
    const float* __restrict__ S, const unsigned short* __restrict__ Frag,
    const float* __restrict__ b2, float* __restrict__ y30)
{
    __shared__ __align__(16) unsigned short p1T[260 * P1TS];   // 37.4 KB
    float* ymat = (float*)p1T;                                  // overlay, phase-2 epilogue
    const int b = blockIdx.x, tid = threadIdx.x;
    const int lane = tid & 63, wv = tid >> 6;
    const float* __restrict__ xb = S + (size_t)b * 3072;
    const bf16x8* fr = (const bf16x8*)Frag;

    // zero pad rows tp=255..259 (read via kk shifts in phase 2)
    if (tid < 180) ((unsigned int*)(p1T + 255 * P1TS))[tid] = 0u;

    // ---- phase 1 ----
    {
        const int n = lane & 31, kg2 = lane >> 5;
        bf16x8 A10 = fr[24 * 64 + lane];
        bf16x8 A11 = fr[25 * 64 + lane];
        #pragma unroll 1
        for (int ntl = wv; ntl < 32; ntl += 4) {
            const int t = ntl * 32 + n;
            union { unsigned int u[4]; bf16x8 v; } bb;
            bb.u[0] = bb.u[1] = bb.u[2] = bb.u[3] = 0u;
            if (t < 1020) {
                const float* xp = xb + 3 * t + kg2 * 8;
                if (kg2 == 0) {     // k=0..7
                    bb.u[0] = pk2(xp[0], xp[1]); bb.u[1] = pk2(xp[2], xp[3]);
                    bb.u[2] = pk2(xp[4], xp[5]); bb.u[3] = pk2(xp[6], xp[7]);
                } else {            // k=8..14 -> x, k=15 -> 1.0 (bias col)
                    bb.u[0] = pk2(xp[0], xp[1]); bb.u[1] = pk2(xp[2], xp[3]);
                    bb.u[2] = pk2(xp[4], xp[5]); bb.u[3] = pk2(xp[6], 1.0f);
                }
            }
            f32x16 z = zero16();
            f32x16 y0 = __builtin_amdgcn_mfma_f32_32x32x16_bf16(A10, bb.v, z, 0, 0, 0);
            f32x16 y1 = __builtin_amdgcn_mfma_f32_32x32x16_bf16(A11, bb.v, z, 0, 0, 0);
            const int t4 = t >> 2;
            #pragma unroll
            for (int g4 = 0; g4 < 4; ++g4) {
                float a0 = maxq(y0[4*g4+0]), a1 = maxq(y0[4*g4+1]);
                float a2 = maxq(y0[4*g4+2]), a3 = maxq(y0[4*g4+3]);
                float c0v = maxq(y1[4*g4+0]), c1v = maxq(y1[4*g4+1]);
                float c2v = maxq(y1[4*g4+2]), c3v = maxq(y1[4*g4+3]);
                if ((n & 3) == 0 && t4 < 255) {
                    int c0 = g4 * 8 + 4 * kg2;
                    unsigned int* d0 = (unsigned int*)(p1T + t4 * P1TS + c0);
                    d0[0] = pk2(a0, a1); d0[1] = pk2(a2, a3);
                    unsigned int* d1 = (unsigned int*)(p1T + t4 * P1TS + c0 + 32);
                    d1[0] = pk2(c0v, c1v); d1[1] = pk2(c2v, c3v);
                }
            }
        }
    }
    __syncthreads();

    // ---- phase 2 ----
    const int m_ = lane & 15, kg16 = lane >> 4;
    f32x4 acc[4][2];
    #pragma unroll
    for (int q = 0; q < 4; ++q) {
        acc[q][0] = (f32x4){0.f, 0.f, 0.f, 0.f};
        acc[q][1] = (f32x4){0.f, 0.f, 0.f, 0.f};
    }
    #pragma unroll 1
    for (int Ks = 0; Ks < 2; ++Ks) {
        bf16x8 Af[10];
        #pragma unroll
        for (int kk = 0; kk < 5; ++kk) {
            Af[kk * 2]     = fr[((kk * 2 + Ks) * 2) * 64 + lane];
            Af[kk * 2 + 1] = fr[((kk * 2 + Ks) * 2 + 1) * 64 + lane];
        }
        #pragma unroll
        for (int kk = 0; kk < 5; ++kk) {
            #pragma unroll
            for (int q = 0; q < 4; ++q) {
                const int row = wv * 64 + q * 16 + m_ + kk;
                const bf16x8 Bf = *(const bf16x8*)(p1T + row * P1TS + Ks * 32 + kg16 * 8);
                acc[q][0] = __builtin_amdgcn_mfma_f32_16x16x32_bf16(Af[kk*2],   Bf, acc[q][0], 0, 0, 0);
                acc[q][1] = __builtin_amdgcn_mfma_f32_16x16x32_bf16(Af[kk*2+1], Bf, acc[q][1], 0, 0, 0);
            }
        }
    }
    __syncthreads();    // all p1T reads done; safe to overlay ymat

    // epilogue: pool4 over t2 (m_ quads) then write ymat[n4][36]
    #pragma unroll
    for (int q = 0; q < 4; ++q) {
        #pragma unroll
        for (int tt = 0; tt < 2; ++tt) {
            float p0 = maxq(acc[q][tt][0]);
            float p1 = maxq(acc[q][tt][1]);
            float p2 = maxq(acc[q][tt][2]);
            float p3 = maxq(acc[q][tt][3]);
            if ((m_ & 3) == 0) {
                int n4 = wv * 16 + q * 4 + (m_ >> 2);
                int f0 = tt * 16 + kg16 * 4;
                *(float4*)(ymat + n4 * 36 + f0) = make_float4(p0, p1, p2, p3);
            }
        }
    }
    __syncthreads();
    if (tid < 30) {
        float s = 0.f;
        #pragma unroll 2
        for (int w = 0; w < 62; ++w) s += ymat[w * 36 + tid];
        y30[(size_t)b * 30 + tid] = s * (1.0f / 62.0f) + b2[tid];
    }
}

// ---------------------------------------------------------------------------
// Heads + LSE soft-OR fusion + masked 4-token attention. 1 wave per b.
// (unchanged — verified)
// ---------------------------------------------------------------------------
__global__ __launch_bounds__(64) void head_kernel(
    const int* __restrict__ pairs,
    const float* __restrict__ hv_g, const float* __restrict__ hp_g,
    const float* __restrict__ y30_g,
    const float* __restrict__ Ws_v, const float* __restrict__ bs_v,
    const float* __restrict__ Wd_v, const float* __restrict__ bd_v,
    const float* __restrict__ Ws_p, const float* __restrict__ bs_p,
    const float* __restrict__ Wd_p, const float* __restrict__ bd_p,
    const float* __restrict__ Wsp, const float* __restrict__ bsp,
    const float* __restrict__ Wa,  const float* __restrict__ ba,
    const float* __restrict__ Wf,  const float* __restrict__ bf,
    float* __restrict__ out)
{
    __shared__ float hv[64], hp[64];
    __shared__ float s0v[32], s0p[32];
    __shared__ float f4[4][32];
    __shared__ float qk[4][192];
    __shared__ float qm[32];
    __shared__ float lg[4][4];
    __shared__ float wsm[4][4];
    __shared__ float ffl[4][32];
    const int b = blockIdx.x;
    const int lane = threadIdx.x;
    const int pf = pairs[b];

    hv[lane] = hv_g[(size_t)b * 64 + lane];
    hp[lane] = hp_g[(size_t)b * 64 + lane];
    __syncthreads();

    if (lane < 30) {
        float a_s = bs_v[lane], a_d = bd_v[lane];
        float p_s = bs_p[lane], p_d = bd_p[lane];
        for (int k = 0; k < 64; ++k) {
            float h = hv[k], g = hp[k];
            a_s = fmaf(h, Ws_v[k*30 + lane], a_s);
            a_d = fmaf(h, Wd_v[k*30 + lane], a_d);
            p_s = fmaf(g, Ws_p[k*30 + lane], p_s);
            p_d = fmaf(g, Wd_p[k*30 + lane], p_d);
        }
        s0v[lane] = a_s;
        s0p[lane] = p_s;
        f4[3][lane] = a_d;
        f4[0][lane] = p_d;
        f4[2][lane] = y30_g[(size_t)b * 30 + lane];
    }
    __syncthreads();

    if (lane < 30) {
        float v_s = bsp[lane], p_s = bsp[lane];
        for (int j = 0; j < 30; ++j) {
            float wj = Wsp[j*30 + lane];
            v_s = fmaf(s0v[j], wj, v_s);
            p_s = fmaf(s0p[j], wj, p_s);
        }
        float h1 = v_s, h2 = p_s, h12 = h1 + h2;
        float m1 = fmaxf(h12, fmaxf(h1, h2));
        float lse1 = m1 + logf(2.f*expf(h12 - m1) + expf(h1 - m1) + expf(h2 - m1));
        float m2 = fmaxf(0.f, fmaxf(h1, h2));
        float lse2 = m2 + logf(2.f*expf(-m2) + expf(h1 - m2) + expf(h2 - m2));
        f4[1][lane] = pf ? (lse1 - lse2) : h2;
    }
    __syncthreads();

    #pragma unroll 1
    for (int t = 0; t < 4; ++t) {
        #pragma unroll 1
        for (int c0 = 0; c0 < 3; ++c0) {
            int c = c0 * 64 + lane;
            float a = ba[c];
            for (int j = 0; j < 30; ++j)
                a = fmaf(f4[t][j], Wa[j*192 + c], a);
            qk[t][c] = a;
        }
    }
    __syncthreads();

    if (lane < 32) {
        float q0 = qk[0][lane], q1 = qk[1][lane], q2 = qk[2][lane], q3 = qk[3][lane];
        qm[lane] = pf ? (q0 + q1 + q2 + q3) * 0.25f
                      : (q0 + q1 + q2) * (1.f / 3.f);
    }
    __syncthreads();

    if (lane < 16) {
        int n = lane >> 2, t = lane & 3;
        float a = 0.f;
        const float* kp = &qk[t][64 + 32*n];
        for (int d = 0; d < 32; ++d) a = fmaf(kp[d], qm[d], a);
        a *= 0.17677669529663687f;
        if (t == 3 && pf == 0) a = -INFINITY;
        lg[n][t] = a;
    }
    __syncthreads();

    if (lane < 4) {
        float l0 = lg[lane][0], l1 = lg[lane][1], l2 = lg[lane][2], l3 = lg[lane][3];
        float m = fmaxf(fmaxf(l0, l1), fmaxf(l2, l3));
        float e0 = expf(l0 - m), e1 = expf(l1 - m), e2 = expf(l2 - m);
        float e3 = expf(l3 - m);
        float s = e0 + e1 + e2 + e3;
        wsm[lane][0] = e0 / s; wsm[lane][1] = e1 / s;
        wsm[lane][2] = e2 / s; wsm[lane][3] = e3 / s;
    }
    __syncthreads();

    #pragma unroll
    for (int r = 0; r < 2; ++r) {
        int n = (lane >> 5) + 2 * r, d = lane & 31;
        float a = 0.f;
        #pragma unroll
        for (int t = 0; t < 4; ++t) a = fmaf(wsm[n][t], qk[t][32 + d], a);
        ffl[n][d] = a;
    }
    __syncthreads();

    if (lane < 4) {
        float a = bf[lane];
        for (int d = 0; d < 32; ++d) a = fmaf(ffl[lane][d], Wf[d*4 + lane], a);
        out[(size_t)b * 4 + lane] = a;
    }
}

// ---------------------------------------------------------------------------
extern "C" void kernel_launch(void* const* d_in, const int* in_sizes, int n_in,
                              void* d_out, int out_size, void* d_ws, size_t ws_size,
                              hipStream_t stream)
{
    const int*   pairs = (const int*)  d_in[0];
    const float* S_V   = (const float*)d_in[1];
    const float* S_P   = (const float*)d_in[2];
    const float* S_P1  = (const float*)d_in[3];
    const float* Wc_v  = (const float*)d_in[4];
    const float* bc_v  = (const float*)d_in[5];
    const float* Ws_v  = (const float*)d_in[6];
    const float* bs_v  = (const float*)d_in[7];
    const float* Wd_v  = (const float*)d_in[8];
    const float* bd_v  = (const float*)d_in[9];
    const float* Wc_p  = (const float*)d_in[10];
    const float* bc_p  = (const float*)d_in[11];
    const float* Ws_p  = (const float*)d_in[12];
    const float* bs_p  = (const float*)d_in[13];
    const float* Wd_p  = (const float*)d_in[14];
    const float* bd_p  = (const float*)d_in[15];
    const float* Wsp   = (const float*)d_in[16];
    const float* bsp   = (const float*)d_in[17];
    const float* W1    = (const float*)d_in[18];
    const float* b1    = (const float*)d_in[19];
    const float* W2    = (const float*)d_in[20];
    const float* b2    = (const float*)d_in[21];
    const float* Wa    = (const float*)d_in[22];
    const float* ba    = (const float*)d_in[23];
    const float* Wf    = (const float*)d_in[24];
    const float* bf    = (const float*)d_in[25];
    float* out = (float*)d_out;

    // ws: h_v[B][64] | h_p[B][64] | y30[B][30] | frags (26 x 64 x 16B)
    float* ws  = (float*)d_ws;
    float* h_v = ws;
    float* h_p = ws + (size_t)B_ * 64;
    float* y30 = ws + (size_t)2 * B_ * 64;
    unsigned short* Frag = (unsigned short*)(ws + (size_t)2 * B_ * 64 + (size_t)B_ * 30);

    prep_frags<<<7, 256, 0, stream>>>(W2, Wc_v, Wc_p, W1, bc_v, bc_p, b1, Frag);
    encode_mfma_kernel<<<dim3(B_, 2), 256, 0, stream>>>(
        S_V, S_P, Frag, h_v, h_p);
    phys_kernel<<<B_, 256, 0, stream>>>(S_P1, Frag, b2, y30);
    head_kernel<<<B_, 64, 0, stream>>>(pairs, h_v, h_p, y30,
                                       Ws_v, bs_v, Wd_v, bd_v,
                                       Ws_p, bs_p, Wd_p, bd_p,
                                       Wsp, bsp, Wa, ba, Wf, bf, out);
}

// Round 2
// 318.868 us; speedup vs baseline: 1.2633x; 1.2023x over previous
//
#include <hip/hip_runtime.h>
#include <math.h>

#define B_   4096

typedef __attribute__((ext_vector_type(8)))  short bf16x8;   // 8 bf16 = 4 VGPR
typedef __attribute__((ext_vector_type(4)))  float f32x4;
typedef __attribute__((ext_vector_type(16))) float f32x16;

// packed f32->bf16 RNE, single VALU instruction (gfx950; no builtin — T12 recipe)
__device__ __forceinline__ unsigned int pk2(float a, float b) {
    unsigned int r;
    asm("v_cvt_pk_bf16_f32 %0, %1, %2" : "=v"(r) : "v"(a), "v"(b));
    return r;
}
__device__ __forceinline__ f32x16 zero16() {
    f32x16 z;
    #pragma unroll
    for (int i = 0; i < 16; ++i) z[i] = 0.f;
    return z;
}
// max of 4 consecutive regs (pool4 along the register/time axis) — tree, depth 2
__device__ __forceinline__ float max4(float a, float b, float c, float d) {
    return fmaxf(fmaxf(a, b), fmaxf(c, d));
}
// tree-sum of relu over 16 regs (short dependency chain)
__device__ __forceinline__ float sumrelu16(const f32x16& y) {
    float t0 = (fmaxf(y[0], 0.f) + fmaxf(y[1], 0.f)) + (fmaxf(y[2], 0.f) + fmaxf(y[3], 0.f));
    float t1 = (fmaxf(y[4], 0.f) + fmaxf(y[5], 0.f)) + (fmaxf(y[6], 0.f) + fmaxf(y[7], 0.f));
    float t2 = (fmaxf(y[8], 0.f) + fmaxf(y[9], 0.f)) + (fmaxf(y[10],0.f) + fmaxf(y[11],0.f));
    float t3 = (fmaxf(y[12],0.f) + fmaxf(y[13],0.f)) + (fmaxf(y[14],0.f) + fmaxf(y[15],0.f));
    return (t0 + t1) + (t2 + t3);
}

// ---------------------------------------------------------------------------
// prep: all MFMA fragments (26 x 64 lanes x 16B). Bias folded at k=15 for
// the 32x32x16 conv fragments (signal supplies a ones-column there).
// A and B fragment lane-layouts are identical on gfx950 (m/n = lane&(M-1),
// k = (lane>>log2M)*8+j), so these bytes serve as EITHER operand.
//  e 0..19 : phys phase-2 (16x16x32), e=(kk*2+Ks)*2+ftile
//  e 20..23: encoder conv (32x32x16), e-20=enc*2+mt; j<9 W, j==15 bias
//  e 24..25: phys phase-1 (32x32x16), mt=e-24;       j<15 W, j==15 bias
// ---------------------------------------------------------------------------
__global__ void prep_frags(const float* __restrict__ W2,
                           const float* __restrict__ Wc_v,
                           const float* __restrict__ Wc_p,
                           const float* __restrict__ W1,
                           const float* __restrict__ bc_v,
                           const float* __restrict__ bc_p,
                           const float* __restrict__ b1,
                           unsigned short* __restrict__ ws_frag)
{
    int gid = blockIdx.x * 256 + threadIdx.x;
    if (gid >= 26 * 64) return;
    int lane = gid & 63, e = gid >> 6;
    unsigned int w[4];
    if (e < 20) {
        int ft = e & 1, Ks = (e >> 1) & 1, kk = e >> 2;
        int m = lane & 15, kg = lane >> 4;
        int f = ft * 16 + m;
        #pragma unroll
        for (int p = 0; p < 4; ++p) {
            int i0 = Ks * 32 + kg * 8 + 2 * p;
            float v0 = (f < 30) ? W2[f * 320 + i0 * 5 + kk] : 0.f;
            float v1 = (f < 30) ? W2[f * 320 + (i0 + 1) * 5 + kk] : 0.f;
            w[p] = pk2(v0, v1);
        }
    } else if (e < 24) {
        int e2 = e - 20, enc = e2 >> 1, mt = e2 & 1;
        const float* Wc = enc ? Wc_p : Wc_v;
        const float* bc = enc ? bc_p : bc_v;
        int c = mt * 32 + (lane & 31), kg = lane >> 5;
        #pragma unroll
        for (int p = 0; p < 4; ++p) {
            int j0 = kg * 8 + 2 * p, j1 = j0 + 1;
            float v0 = (j0 < 9) ? Wc[c * 9 + (j0 % 3) * 3 + (j0 / 3)] : 0.f;
            float v1 = (j1 < 9) ? Wc[c * 9 + (j1 % 3) * 3 + (j1 / 3)]
                                : (j1 == 15 ? bc[c] : 0.f);
            w[p] = pk2(v0, v1);
        }
    } else {
        int mt = e - 24;
        int c = mt * 32 + (lane & 31), kg = lane >> 5;
        #pragma unroll
        for (int p = 0; p < 4; ++p) {
            int j0 = kg * 8 + 2 * p, j1 = j0 + 1;
            float v0 = (j0 < 15) ? W1[c * 15 + (j0 % 3) * 5 + (j0 / 3)] : 0.f;
            float v1 = (j1 < 15) ? W1[c * 15 + (j1 % 3) * 5 + (j1 / 3)]
                                 : (j1 == 15 ? b1[c] : 0.f);
            w[p] = pk2(v0, v1);
        }
    }
    ((uint4*)ws_frag)[gid] = make_uint4(w[0], w[1], w[2], w[3]);
}

// ---------------------------------------------------------------------------
// Encoder: conv(3->64,K=3)+bias (in-K) + ReLU + mean via 32x32x16 MFMA.
// SWAPPED operands: A = signal (time on M/rows), B = weights (channel on N).
// Time lands on the REGISTER axis -> mean(relu) is a per-lane scalar sum;
// the old 34.8KB hmat transpose is replaced by a 2KB cross-wave reduce.
// ---------------------------------------------------------------------------
__global__ __launch_bounds__(256, 6) void encode_mfma_kernel(
    const float* __restrict__ S_V, const float* __restrict__ S_P,
    const unsigned short* __restrict__ Frag,
    float* __restrict__ hv, float* __restrict__ hp)
{
    __shared__ float red[2][4][64];     // 2 KB
    const int enc = blockIdx.y;
    const float* __restrict__ S = enc ? S_P : S_V;
    float* hout = enc ? hp : hv;
    const int b = blockIdx.x, tid = threadIdx.x;
    const int lane = tid & 63, wv = tid >> 6;
    const int n = lane & 31, kg = lane >> 5;
    const float* __restrict__ xb = S + (size_t)b * 3072;

    const bf16x8* fr = (const bf16x8*)Frag;
    bf16x8 Bf0 = fr[(20 + enc * 2) * 64 + lane];   // weights ch 0..31 (as B)
    bf16x8 Bf1 = fr[(21 + enc * 2) * 64 + lane];   // weights ch 32..63

    float s0 = 0.f, s1 = 0.f;

    #pragma unroll 1
    for (int nt = wv; nt < 32; nt += 4) {
        const int t = nt * 32 + n;                 // n = time row of A
        union { unsigned int u[4]; bf16x8 v; } bb;
        bb.u[0] = bb.u[1] = bb.u[2] = bb.u[3] = 0u;
        if (t < 1022) {
            const float* xp = xb + 3 * t;
            if (kg == 0) {          // k=0..7 -> x[3t..3t+7]
                bb.u[0] = pk2(xp[0], xp[1]); bb.u[1] = pk2(xp[2], xp[3]);
                bb.u[2] = pk2(xp[4], xp[5]); bb.u[3] = pk2(xp[6], xp[7]);
            } else {                // k=8 -> x[3t+8]; k=15 -> 1.0 (bias col)
                bb.u[0] = pk2(xp[8], 0.f);
                bb.u[3] = 0x3F800000u;   // packed (0.0, 1.0) in bf16
            }
        }
        f32x16 z = zero16();
        f32x16 y0 = __builtin_amdgcn_mfma_f32_32x32x16_bf16(bb.v, Bf0, z, 0, 0, 0);
        f32x16 y1 = __builtin_amdgcn_mfma_f32_32x32x16_bf16(bb.v, Bf1, z, 0, 0, 0);
        s0 += sumrelu16(y0);       // lane holds channel n   (16 time rows)
        s1 += sumrelu16(y1);       // lane holds channel n+32
    }

    red[0][wv][lane] = s0;
    red[1][wv][lane] = s1;
    __syncthreads();
    if (tid < 64) {                 // tid = channel c
        int half = tid >> 5, c32 = tid & 31;
        float s = 0.f;
        #pragma unroll
        for (int w = 0; w < 4; ++w)
            s += red[half][w][c32] + red[half][w][c32 + 32];
        hout[(size_t)b * 64 + tid] = s * (1.0f / 1022.0f);
    }
}

// ---------------------------------------------------------------------------
// Physical model, SWAPPED operands throughout (time on register axis).
// Phase 1: conv(3->64,K=5)+bias via 32x32x16 MFMA(A=signal, B=weights);
//   pool4 = max of 4 consecutive acc regs (pure VALU tree, no DPP);
//   every lane stores 2 bf16 per pool group (its channel n and n+32).
// Phase 2: 5 shifted 16x16x32 MFMA(A=p1T rows, B=W2 frags); pool4 = max of
//   the lane's 4 acc regs; scalar stores into ymat.
// ---------------------------------------------------------------------------
#define P1TS 72
__global__ __launch_bounds__(256, 4) void phys_kernel(
    const float* __restrict__ S, const unsigned short* __restrict__ Frag,
    const float* __restrict__ b2, float* __restrict__ y30)
{
    __shared__ __align__(16) unsigned short p1T[260 * P1TS];   // 37.4 KB
    float* ymat = (float*)p1T;                                  // overlay, phase-2 epilogue
    const int b = blockIdx.x, tid = threadIdx.x;
    const int lane = tid & 63, wv = tid >> 6;
    const float* __restrict__ xb = S + (size_t)b * 3072;
    const bf16x8* fr = (const bf16x8*)Frag;

    // zero pad rows tp=255..259 (read via kk shifts in phase 2)
    if (tid < 180) ((unsigned int*)(p1T + 255 * P1TS))[tid] = 0u;

    // ---- phase 1 ----
    {
        const int n = lane & 31, kg2 = lane >> 5;
        bf16x8 W10 = fr[24 * 64 + lane];    // weights ch 0..31  (as B)
        bf16x8 W11 = fr[25 * 64 + lane];    // weights ch 32..63
        #pragma unroll 1
        for (int ntl = wv; ntl < 32; ntl += 4) {
            const int t = ntl * 32 + n;      // n = time row of A
            union { unsigned int u[4]; bf16x8 v; } bb;
            bb.u[0] = bb.u[1] = bb.u[2] = bb.u[3] = 0u;
            if (t < 1020) {
                const float* xp = xb + 3 * t + kg2 * 8;
                if (kg2 == 0) {     // k=0..7
                    bb.u[0] = pk2(xp[0], xp[1]); bb.u[1] = pk2(xp[2], xp[3]);
                    bb.u[2] = pk2(xp[4], xp[5]); bb.u[3] = pk2(xp[6], xp[7]);
                } else {            // k=8..14 -> x, k=15 -> 1.0 (bias col)
                    bb.u[0] = pk2(xp[0], xp[1]); bb.u[1] = pk2(xp[2], xp[3]);
                    bb.u[2] = pk2(xp[4], xp[5]); bb.u[3] = pk2(xp[6], 1.0f);
                }
            }
            f32x16 z = zero16();
            // D[t][c]: lane = channel (col), regs = 16 time rows
            f32x16 y0 = __builtin_amdgcn_mfma_f32_32x32x16_bf16(bb.v, W10, z, 0, 0, 0);
            f32x16 y1 = __builtin_amdgcn_mfma_f32_32x32x16_bf16(bb.v, W11, z, 0, 0, 0);
            // regs {4g..4g+3} = rows {8g+4kg2 .. +3} = exactly one pool4 group
            #pragma unroll
            for (int g4 = 0; g4 < 4; ++g4) {
                const int t4 = ntl * 8 + 2 * g4 + kg2;
                if (t4 < 255) {
                    float p0 = max4(y0[4*g4+0], y0[4*g4+1], y0[4*g4+2], y0[4*g4+3]);
                    float p1 = max4(y1[4*g4+0], y1[4*g4+1], y1[4*g4+2], y1[4*g4+3]);
                    unsigned int r = pk2(p0, p1);
                    unsigned short* d = p1T + t4 * P1TS + n;
                    d[0]  = (unsigned short)r;          // channel n
                    d[32] = (unsigned short)(r >> 16);  // channel n+32
                }
            }
        }
    }
    __syncthreads();

    // ---- phase 2 ----
    const int m_ = lane & 15, kg16 = lane >> 4;
    f32x4 acc[4][2];
    #pragma unroll
    for (int q = 0; q < 4; ++q) {
        acc[q][0] = (f32x4){0.f, 0.f, 0.f, 0.f};
        acc[q][1] = (f32x4){0.f, 0.f, 0.f, 0.f};
    }
    #pragma unroll 1
    for (int Ks = 0; Ks < 2; ++Ks) {
        bf16x8 Wf[10];
        #pragma unroll
        for (int kk = 0; kk < 5; ++kk) {
            Wf[kk * 2]     = fr[((kk * 2 + Ks) * 2) * 64 + lane];
            Wf[kk * 2 + 1] = fr[((kk * 2 + Ks) * 2 + 1) * 64 + lane];
        }
        #pragma unroll
        for (int kk = 0; kk < 5; ++kk) {
            #pragma unroll
            for (int q = 0; q < 4; ++q) {
                const int row = wv * 64 + q * 16 + m_ + kk;   // m_ = time row of A
                const bf16x8 Pf = *(const bf16x8*)(p1T + row * P1TS + Ks * 32 + kg16 * 8);
                // D[t][f]: lane&15 = feature (col), kg16*4+reg = time row
                acc[q][0] = __builtin_amdgcn_mfma_f32_16x16x32_bf16(Pf, Wf[kk*2],   acc[q][0], 0, 0, 0);
                acc[q][1] = __builtin_amdgcn_mfma_f32_16x16x32_bf16(Pf, Wf[kk*2+1], acc[q][1], 0, 0, 0);
            }
        }
    }
    __syncthreads();    // all p1T reads done; safe to overlay ymat

    // epilogue: lane's 4 acc regs = rows {kg16*4..+3} = one pool4 group
    #pragma unroll
    for (int q = 0; q < 4; ++q) {
        #pragma unroll
        for (int ft = 0; ft < 2; ++ft) {
            f32x4 a = acc[q][ft];
            float p = max4(a[0], a[1], a[2], a[3]);
            int n4 = wv * 16 + q * 4 + kg16;
            ymat[n4 * 36 + ft * 16 + m_] = p;   // m_ = feature here
        }
    }
    __syncthreads();
    if (tid < 30) {
        float s = 0.f;
        #pragma unroll 2
        for (int w = 0; w < 62; ++w) s += ymat[w * 36 + tid];
        y30[(size_t)b * 30 + tid] = s * (1.0f / 62.0f) + b2[tid];
    }
}

// ---------------------------------------------------------------------------
// Heads + LSE soft-OR fusion + masked 4-token attention. 1 wave per b.
// (unchanged — verified)
// ---------------------------------------------------------------------------
__global__ __launch_bounds__(64) void head_kernel(
    const int* __restrict__ pairs,
    const float* __restrict__ hv_g, const float* __restrict__ hp_g,
    const float* __restrict__ y30_g,
    const float* __restrict__ Ws_v, const float* __restrict__ bs_v,
    const float* __restrict__ Wd_v, const float* __restrict__ bd_v,
    const float* __restrict__ Ws_p, const float* __restrict__ bs_p,
    const float* __restrict__ Wd_p, const float* __restrict__ bd_p,
    const float* __restrict__ Wsp, const float* __restrict__ bsp,
    const float* __restrict__ Wa,  const float* __restrict__ ba,
    const float* __restrict__ Wf,  const float* __restrict__ bf,
    float* __restrict__ out)
{
    __shared__ float hv[64], hp[64];
    __shared__ float s0v[32], s0p[32];
    __shared__ float f4[4][32];
    __shared__ float qk[4][192];
    __shared__ float qm[32];
    __shared__ float lg[4][4];
    __shared__ float wsm[4][4];
    __shared__ float ffl[4][32];
    const int b = blockIdx.x;
    const int lane = threadIdx.x;
    const int pf = pairs[b];

    hv[lane] = hv_g[(size_t)b * 64 + lane];
    hp[lane] = hp_g[(size_t)b * 64 + lane];
    __syncthreads();

    if (lane < 30) {
        float a_s = bs_v[lane], a_d = bd_v[lane];
        float p_s = bs_p[lane], p_d = bd_p[lane];
        for (int k = 0; k < 64; ++k) {
            float h = hv[k], g = hp[k];
            a_s = fmaf(h, Ws_v[k*30 + lane], a_s);
            a_d = fmaf(h, Wd_v[k*30 + lane], a_d);
            p_s = fmaf(g, Ws_p[k*30 + lane], p_s);
            p_d = fmaf(g, Wd_p[k*30 + lane], p_d);
        }
        s0v[lane] = a_s;
        s0p[lane] = p_s;
        f4[3][lane] = a_d;
        f4[0][lane] = p_d;
        f4[2][lane] = y30_g[(size_t)b * 30 + lane];
    }
    __syncthreads();

    if (lane < 30) {
        float v_s = bsp[lane], p_s = bsp[lane];
        for (int j = 0; j < 30; ++j) {
            float wj = Wsp[j*30 + lane];
            v_s = fmaf(s0v[j], wj, v_s);
            p_s = fmaf(s0p[j], wj, p_s);
        }
        float h1 = v_s, h2 = p_s, h12 = h1 + h2;
        float m1 = fmaxf(h12, fmaxf(h1, h2));
        float lse1 = m1 + logf(2.f*expf(h12 - m1) + expf(h1 - m1) + expf(h2 - m1));
        float m2 = fmaxf(0.f, fmaxf(h1, h2));
        float lse2 = m2 + logf(2.f*expf(-m2) + expf(h1 - m2) + expf(h2 - m2));
        f4[1][lane] = pf ? (lse1 - lse2) : h2;
    }
    __syncthreads();

    #pragma unroll 1
    for (int t = 0; t < 4; ++t) {
        #pragma unroll 1
        for (int c0 = 0; c0 < 3; ++c0) {
            int c = c0 * 64 + lane;
            float a = ba[c];
            for (int j = 0; j < 30; ++j)
                a = fmaf(f4[t][j], Wa[j*192 + c], a);
            qk[t][c] = a;
        }
    }
    __syncthreads();

    if (lane < 32) {
        float q0 = qk[0][lane], q1 = qk[1][lane], q2 = qk[2][lane], q3 = qk[3][lane];
        qm[lane] = pf ? (q0 + q1 + q2 + q3) * 0.25f
                      : (q0 + q1 + q2) * (1.f / 3.f);
    }
    __syncthreads();

    if (lane < 16) {
        int n = lane >> 2, t = lane & 3;
        float a = 0.f;
        const float* kp = &qk[t][64 + 32*n];
        for (int d = 0; d < 32; ++d) a = fmaf(kp[d], qm[d], a);
        a *= 0.17677669529663687f;
        if (t == 3 && pf == 0) a = -INFINITY;
        lg[n][t] = a;
    }
    __syncthreads();

    if (lane < 4) {
        float l0 = lg[lane][0], l1 = lg[lane][1], l2 = lg[lane][2], l3 = lg[lane][3];
        float m = fmaxf(fmaxf(l0, l1), fmaxf(l2, l3));
        float e0 = expf(l0 - m), e1 = expf(l1 - m), e2 = expf(l2 - m);
        float e3 = expf(l3 - m);
        float s = e0 + e1 + e2 + e3;
        wsm[lane][0] = e0 / s; wsm[lane][1] = e1 / s;
        wsm[lane][2] = e2 / s; wsm[lane][3] = e3 / s;
    }
    __syncthreads();

    #pragma unroll
    for (int r = 0; r < 2; ++r) {
        int n = (lane >> 5) + 2 * r, d = lane & 31;
        float a = 0.f;
        #pragma unroll
        for (int t = 0; t < 4; ++t) a = fmaf(wsm[n][t], qk[t][32 + d], a);
        ffl[n][d] = a;
    }
    __syncthreads();

    if (lane < 4) {
        float a = bf[lane];
        for (int d = 0; d < 32; ++d) a = fmaf(ffl[lane][d], Wf[d*4 + lane], a);
        out[(size_t)b * 4 + lane] = a;
    }
}

// ---------------------------------------------------------------------------
extern "C" void kernel_launch(void* const* d_in, const int* in_sizes, int n_in,
                              void* d_out, int out_size, void* d_ws, size_t ws_size,
                              hipStream_t stream)
{
    const int*   pairs = (const int*)  d_in[0];
    const float* S_V   = (const float*)d_in[1];
    const float* S_P   = (const float*)d_in[2];
    const float* S_P1  = (const float*)d_in[3];
    const float* Wc_v  = (const float*)d_in[4];
    const float* bc_v  = (const float*)d_in[5];
    const float* Ws_v  = (const float*)d_in[6];
    const float* bs_v  = (const float*)d_in[7];
    const float* Wd_v  = (const float*)d_in[8];
    const float* bd_v  = (const float*)d_in[9];
    const float* Wc_p  = (const float*)d_in[10];
    const float* bc_p  = (const float*)d_in[11];
    const float* Ws_p  = (const float*)d_in[12];
    const float* bs_p  = (const float*)d_in[13];
    const float* Wd_p  = (const float*)d_in[14];
    const float* bd_p  = (const float*)d_in[15];
    const float* Wsp   = (const float*)d_in[16];
    const float* bsp   = (const float*)d_in[17];
    const float* W1    = (const float*)d_in[18];
    const float* b1    = (const float*)d_in[19];
    const float* W2    = (const float*)d_in[20];
    const float* b2    = (const float*)d_in[21];
    const float* Wa    = (const float*)d_in[22];
    const float* ba    = (const float*)d_in[23];
    const float* Wf    = (const float*)d_in[24];
    const float* bf    = (const float*)d_in[25];
    float* out = (float*)d_out;

    // ws: h_v[B][64] | h_p[B][64] | y30[B][30] | frags (26 x 64 x 16B)
    float* ws  = (float*)d_ws;
    float* h_v = ws;
    float* h_p = ws + (size_t)B_ * 64;
    float* y30 = ws + (size_t)2 * B_ * 64;
    unsigned short* Frag = (unsigned short*)(ws + (size_t)2 * B_ * 64 + (size_t)B_ * 30);

    prep_frags<<<7, 256, 0, stream>>>(W2, Wc_v, Wc_p, W1, bc_v, bc_p, b1, Frag);
    encode_mfma_kernel<<<dim3(B_, 2), 256, 0, stream>>>(
        S_V, S_P, Frag, h_v, h_p);
    phys_kernel<<<B_, 256, 0, stream>>>(S_P1, Frag, b2, y30);
    head_kernel<<<B_, 64, 0, stream>>>(pairs, h_v, h_p, y30,
                                       Ws_v, bs_v, Wd_v, bd_v,
                                       Ws_p, bs_p, Wd_p, bd_p,
                                       Wsp, bsp, Wa, ba, Wf, bf, out);
}

// Round 3
// 314.300 us; speedup vs baseline: 1.2816x; 1.0145x over previous
//
#include <hip/hip_runtime.h>
#include <math.h>

#define B_   4096

typedef __attribute__((ext_vector_type(8)))  short bf16x8;   // 8 bf16 = 4 VGPR
typedef __attribute__((ext_vector_type(4)))  float f32x4;
typedef __attribute__((ext_vector_type(16))) float f32x16;

// packed f32->bf16 RNE, single VALU instruction (gfx950; no builtin — T12 recipe)
__device__ __forceinline__ unsigned int pk2(float a, float b) {
    unsigned int r;
    asm("v_cvt_pk_bf16_f32 %0, %1, %2" : "=v"(r) : "v"(a), "v"(b));
    return r;
}
__device__ __forceinline__ f32x16 zero16() {
    f32x16 z;
    #pragma unroll
    for (int i = 0; i < 16; ++i) z[i] = 0.f;
    return z;
}
// max of 4 consecutive regs (pool4 along the register/time axis) — tree, depth 2
__device__ __forceinline__ float max4(float a, float b, float c, float d) {
    return fmaxf(fmaxf(a, b), fmaxf(c, d));
}
// tree-sum of relu over 16 regs (short dependency chain)
__device__ __forceinline__ float sumrelu16(const f32x16& y) {
    float t0 = (fmaxf(y[0], 0.f) + fmaxf(y[1], 0.f)) + (fmaxf(y[2], 0.f) + fmaxf(y[3], 0.f));
    float t1 = (fmaxf(y[4], 0.f) + fmaxf(y[5], 0.f)) + (fmaxf(y[6], 0.f) + fmaxf(y[7], 0.f));
    float t2 = (fmaxf(y[8], 0.f) + fmaxf(y[9], 0.f)) + (fmaxf(y[10],0.f) + fmaxf(y[11],0.f));
    float t3 = (fmaxf(y[12],0.f) + fmaxf(y[13],0.f)) + (fmaxf(y[14],0.f) + fmaxf(y[15],0.f));
    return (t0 + t1) + (t2 + t3);
}

// ---------------------------------------------------------------------------
// prep: all MFMA fragments (26 x 64 lanes x 16B). Bias folded at k=15 for
// the 32x32x16 conv fragments (signal supplies a ones-column there).
// A and B fragment lane-layouts are identical on gfx950, so these bytes
// serve as EITHER operand.
//  e 0..19 : phys phase-2 (16x16x32), e=(kk*2+Ks)*2+ftile
//  e 20..23: encoder conv (32x32x16), e-20=enc*2+mt; j<9 W, j==15 bias
//  e 24..25: phys phase-1 (32x32x16), mt=e-24;       j<15 W, j==15 bias
// ---------------------------------------------------------------------------
__global__ void prep_frags(const float* __restrict__ W2,
                           const float* __restrict__ Wc_v,
                           const float* __restrict__ Wc_p,
                           const float* __restrict__ W1,
                           const float* __restrict__ bc_v,
                           const float* __restrict__ bc_p,
                           const float* __restrict__ b1,
                           unsigned short* __restrict__ ws_frag)
{
    int gid = blockIdx.x * 256 + threadIdx.x;
    if (gid >= 26 * 64) return;
    int lane = gid & 63, e = gid >> 6;
    unsigned int w[4];
    if (e < 20) {
        int ft = e & 1, Ks = (e >> 1) & 1, kk = e >> 2;
        int m = lane & 15, kg = lane >> 4;
        int f = ft * 16 + m;
        #pragma unroll
        for (int p = 0; p < 4; ++p) {
            int i0 = Ks * 32 + kg * 8 + 2 * p;
            float v0 = (f < 30) ? W2[f * 320 + i0 * 5 + kk] : 0.f;
            float v1 = (f < 30) ? W2[f * 320 + (i0 + 1) * 5 + kk] : 0.f;
            w[p] = pk2(v0, v1);
        }
    } else if (e < 24) {
        int e2 = e - 20, enc = e2 >> 1, mt = e2 & 1;
        const float* Wc = enc ? Wc_p : Wc_v;
        const float* bc = enc ? bc_p : bc_v;
        int c = mt * 32 + (lane & 31), kg = lane >> 5;
        #pragma unroll
        for (int p = 0; p < 4; ++p) {
            int j0 = kg * 8 + 2 * p, j1 = j0 + 1;
            float v0 = (j0 < 9) ? Wc[c * 9 + (j0 % 3) * 3 + (j0 / 3)] : 0.f;
            float v1 = (j1 < 9) ? Wc[c * 9 + (j1 % 3) * 3 + (j1 / 3)]
                                : (j1 == 15 ? bc[c] : 0.f);
            w[p] = pk2(v0, v1);
        }
    } else {
        int mt = e - 24;
        int c = mt * 32 + (lane & 31), kg = lane >> 5;
        #pragma unroll
        for (int p = 0; p < 4; ++p) {
            int j0 = kg * 8 + 2 * p, j1 = j0 + 1;
            float v0 = (j0 < 15) ? W1[c * 15 + (j0 % 3) * 5 + (j0 / 3)] : 0.f;
            float v1 = (j1 < 15) ? W1[c * 15 + (j1 % 3) * 5 + (j1 / 3)]
                                 : (j1 == 15 ? b1[c] : 0.f);
            w[p] = pk2(v0, v1);
        }
    }
    ((uint4*)ws_frag)[gid] = make_uint4(w[0], w[1], w[2], w[3]);
}

// ---------------------------------------------------------------------------
// Encoder: conv(3->64,K=3)+bias (in-K) + ReLU + mean via 32x32x16 MFMA.
// Signal staged to LDS cooperatively (coalesced float2), B-fragments built
// from LDS (conflict-free: bank 3n%32 bijective). 512 threads, 8 waves,
// LDS 16 KB -> 4 blocks/CU = 100% occupancy.
// ---------------------------------------------------------------------------
__global__ __launch_bounds__(512, 8) void encode_mfma_kernel(
    const float* __restrict__ S_V, const float* __restrict__ S_P,
    const unsigned short* __restrict__ Frag,
    float* __restrict__ hv, float* __restrict__ hp)
{
    __shared__ __align__(16) float sig[3072];   // 12 KB
    __shared__ float red[2][8][64];             // 4 KB
    const int enc = blockIdx.y;
    const float* __restrict__ S = enc ? S_P : S_V;
    float* hout = enc ? hp : hv;
    const int b = blockIdx.x, tid = threadIdx.x;
    const int lane = tid & 63, wv = tid >> 6;
    const int n = lane & 31, kg = lane >> 5;
    const float* __restrict__ xb = S + (size_t)b * 3072;

    // stage signal: 1536 float2, fully coalesced
    #pragma unroll
    for (int i = 0; i < 3; ++i) {
        int idx = tid + i * 512;
        ((float2*)sig)[idx] = ((const float2*)xb)[idx];
    }
    const bf16x8* fr = (const bf16x8*)Frag;
    bf16x8 Bf0 = fr[(20 + enc * 2) * 64 + lane];   // weights ch 0..31 (as B)
    bf16x8 Bf1 = fr[(21 + enc * 2) * 64 + lane];   // weights ch 32..63
    __syncthreads();

    float s0 = 0.f, s1 = 0.f;

    #pragma unroll 1
    for (int nt = wv; nt < 32; nt += 8) {
        const int t = nt * 32 + n;                 // n = time row of A
        union { unsigned int u[4]; bf16x8 v; } bb;
        bb.u[0] = bb.u[1] = bb.u[2] = bb.u[3] = 0u;
        if (t < 1022) {
            const float* xp = sig + 3 * t;
            if (kg == 0) {          // k=0..7 -> x[3t..3t+7]
                bb.u[0] = pk2(xp[0], xp[1]); bb.u[1] = pk2(xp[2], xp[3]);
                bb.u[2] = pk2(xp[4], xp[5]); bb.u[3] = pk2(xp[6], xp[7]);
            } else {                // k=8 -> x[3t+8]; k=15 -> 1.0 (bias col)
                bb.u[0] = pk2(xp[8], 0.f);
                bb.u[3] = 0x3F800000u;   // packed (0.0, 1.0) in bf16
            }
        }
        f32x16 y0 = __builtin_amdgcn_mfma_f32_32x32x16_bf16(bb.v, Bf0, zero16(), 0, 0, 0);
        f32x16 y1 = __builtin_amdgcn_mfma_f32_32x32x16_bf16(bb.v, Bf1, zero16(), 0, 0, 0);
        s0 += sumrelu16(y0);       // lane holds channel n   (16 time rows)
        s1 += sumrelu16(y1);       // lane holds channel n+32
    }

    red[0][wv][lane] = s0;
    red[1][wv][lane] = s1;
    __syncthreads();
    if (tid < 64) {                 // tid = channel c
        int half = tid >> 5, c32 = tid & 31;
        float s = 0.f;
        #pragma unroll
        for (int w = 0; w < 8; ++w)
            s += red[half][w][c32] + red[half][w][c32 + 32];
        hout[(size_t)b * 64 + tid] = s * (1.0f / 1022.0f);
    }
}

// ---------------------------------------------------------------------------
// Physical model, time on register axis. 512 threads (8 waves) -> 4 blocks/CU
// = 100% theoretical occupancy (LDS 37.4 KB). Phase 1: 4 iters/wave with
// 1-deep register prefetch of the next iteration's 8 signal floats; y0 pooled
// and stored before y1 is computed to keep VGPR <= 64 (launch_bounds 512,8).
// Phase 2: acc[2][2] per wave, rows wv*32 + q*16.
// ---------------------------------------------------------------------------
#define P1TS 72
__global__ __launch_bounds__(512, 8) void phys_kernel(
    const float* __restrict__ S, const unsigned short* __restrict__ Frag,
    const float* __restrict__ b2, float* __restrict__ y30)
{
    __shared__ __align__(16) unsigned short p1T[260 * P1TS];   // 37.4 KB
    float* ymat = (float*)p1T;                                  // overlay, phase-2 epilogue
    const int b = blockIdx.x, tid = threadIdx.x;
    const int lane = tid & 63, wv = tid >> 6;                   // wv 0..7
    const float* __restrict__ xb = S + (size_t)b * 3072;
    const bf16x8* fr = (const bf16x8*)Frag;

    // zero pad rows tp=255..259 (read via kk shifts in phase 2)
    if (tid < 180) ((unsigned int*)(p1T + 255 * P1TS))[tid] = 0u;

    // ---- phase 1 ----
    {
        const int n = lane & 31, kg2 = lane >> 5;
        bf16x8 W10 = fr[24 * 64 + lane];    // weights ch 0..31  (as B)
        bf16x8 W11 = fr[25 * 64 + lane];    // weights ch 32..63
        // unified per-lane load: a[0..6] = x[3t+kg2*8 ..], a[7] = x[..+7] or 1.0
        float a[8];
        {   // prologue: ntl = wv  (t <= 255, always valid)
            const int t0 = wv * 32 + n;
            const float* xp = xb + 3 * t0 + kg2 * 8;
            #pragma unroll
            for (int i = 0; i < 7; ++i) a[i] = xp[i];
            a[7] = kg2 ? 1.0f : xp[7];
        }
        #pragma unroll 1
        for (int ntl = wv; ntl < 32; ntl += 8) {
            // prefetch next iteration's values (1-deep pipeline)
            float nx[8];
            const int ntn = ntl + 8;
            if (ntn < 32) {
                const int tn = ntn * 32 + n;
                const float* xq = xb + 3 * tn + kg2 * 8;
                const bool ok = tn < 1020;
                #pragma unroll
                for (int i = 0; i < 7; ++i) nx[i] = ok ? xq[i] : 0.f;
                nx[7] = kg2 ? 1.0f : (ok ? xq[7] : 0.f);
            }
            union { unsigned int u[4]; bf16x8 v; } bb;
            bb.u[0] = pk2(a[0], a[1]); bb.u[1] = pk2(a[2], a[3]);
            bb.u[2] = pk2(a[4], a[5]); bb.u[3] = pk2(a[6], a[7]);
            // D[t][c]: lane = channel (col), regs = 16 time rows
            f32x16 y0 = __builtin_amdgcn_mfma_f32_32x32x16_bf16(bb.v, W10, zero16(), 0, 0, 0);
            #pragma unroll
            for (int g4 = 0; g4 < 4; ++g4) {
                const int t4 = ntl * 8 + 2 * g4 + kg2;
                if (t4 < 255) {
                    float p0 = max4(y0[4*g4+0], y0[4*g4+1], y0[4*g4+2], y0[4*g4+3]);
                    p1T[t4 * P1TS + n] = (unsigned short)pk2(p0, p0);
                }
            }
            f32x16 y1 = __builtin_amdgcn_mfma_f32_32x32x16_bf16(bb.v, W11, zero16(), 0, 0, 0);
            #pragma unroll
            for (int g4 = 0; g4 < 4; ++g4) {
                const int t4 = ntl * 8 + 2 * g4 + kg2;
                if (t4 < 255) {
                    float p1 = max4(y1[4*g4+0], y1[4*g4+1], y1[4*g4+2], y1[4*g4+3]);
                    p1T[t4 * P1TS + n + 32] = (unsigned short)pk2(p1, p1);
                }
            }
            if (ntn < 32) {
                #pragma unroll
                for (int i = 0; i < 8; ++i) a[i] = nx[i];
            }
        }
    }
    __syncthreads();

    // ---- phase 2 ----
    const int m_ = lane & 15, kg16 = lane >> 4;
    f32x4 acc[2][2];
    #pragma unroll
    for (int q = 0; q < 2; ++q) {
        acc[q][0] = (f32x4){0.f, 0.f, 0.f, 0.f};
        acc[q][1] = (f32x4){0.f, 0.f, 0.f, 0.f};
    }
    #pragma unroll 1
    for (int Ks = 0; Ks < 2; ++Ks) {
        bf16x8 Wf[10];
        #pragma unroll
        for (int kk = 0; kk < 5; ++kk) {
            Wf[kk * 2]     = fr[((kk * 2 + Ks) * 2) * 64 + lane];
            Wf[kk * 2 + 1] = fr[((kk * 2 + Ks) * 2 + 1) * 64 + lane];
        }
        #pragma unroll
        for (int kk = 0; kk < 5; ++kk) {
            #pragma unroll
            for (int q = 0; q < 2; ++q) {
                const int row = wv * 32 + q * 16 + m_ + kk;   // m_ = time row of A
                const bf16x8 Pf = *(const bf16x8*)(p1T + row * P1TS + Ks * 32 + kg16 * 8);
                // D[t][f]: lane&15 = feature (col), kg16*4+reg = time row
                acc[q][0] = __builtin_amdgcn_mfma_f32_16x16x32_bf16(Pf, Wf[kk*2],   acc[q][0], 0, 0, 0);
                acc[q][1] = __builtin_amdgcn_mfma_f32_16x16x32_bf16(Pf, Wf[kk*2+1], acc[q][1], 0, 0, 0);
            }
        }
    }
    __syncthreads();    // all p1T reads done; safe to overlay ymat

    // epilogue: lane's 4 acc regs = rows {kg16*4..+3} = one pool4 group
    #pragma unroll
    for (int q = 0; q < 2; ++q) {
        #pragma unroll
        for (int ft = 0; ft < 2; ++ft) {
            f32x4 av = acc[q][ft];
            float p = max4(av[0], av[1], av[2], av[3]);
            int n4 = wv * 8 + q * 4 + kg16;
            ymat[n4 * 36 + ft * 16 + m_] = p;   // m_ = feature here
        }
    }
    __syncthreads();
    if (tid < 30) {
        float s = 0.f;
        #pragma unroll 2
        for (int w = 0; w < 62; ++w) s += ymat[w * 36 + tid];
        y30[(size_t)b * 30 + tid] = s * (1.0f / 62.0f) + b2[tid];
    }
}

// ---------------------------------------------------------------------------
// Heads + LSE soft-OR fusion + masked 4-token attention. 1 wave per b.
// (unchanged — verified)
// ---------------------------------------------------------------------------
__global__ __launch_bounds__(64) void head_kernel(
    const int* __restrict__ pairs,
    const float* __restrict__ hv_g, const float* __restrict__ hp_g,
    const float* __restrict__ y30_g,
    const float* __restrict__ Ws_v, const float* __restrict__ bs_v,
    const float* __restrict__ Wd_v, const float* __restrict__ bd_v,
    const float* __restrict__ Ws_p, const float* __restrict__ bs_p,
    const float* __restrict__ Wd_p, const float* __restrict__ bd_p,
    const float* __restrict__ Wsp, const float* __restrict__ bsp,
    const float* __restrict__ Wa,  const float* __restrict__ ba,
    const float* __restrict__ Wf,  const float* __restrict__ bf,
    float* __restrict__ out)
{
    __shared__ float hv[64], hp[64];
    __shared__ float s0v[32], s0p[32];
    __shared__ float f4[4][32];
    __shared__ float qk[4][192];
    __shared__ float qm[32];
    __shared__ float lg[4][4];
    __shared__ float wsm[4][4];
    __shared__ float ffl[4][32];
    const int b = blockIdx.x;
    const int lane = threadIdx.x;
    const int pf = pairs[b];

    hv[lane] = hv_g[(size_t)b * 64 + lane];
    hp[lane] = hp_g[(size_t)b * 64 + lane];
    __syncthreads();

    if (lane < 30) {
        float a_s = bs_v[lane], a_d = bd_v[lane];
        float p_s = bs_p[lane], p_d = bd_p[lane];
        for (int k = 0; k < 64; ++k) {
            float h = hv[k], g = hp[k];
            a_s = fmaf(h, Ws_v[k*30 + lane], a_s);
            a_d = fmaf(h, Wd_v[k*30 + lane], a_d);
            p_s = fmaf(g, Ws_p[k*30 + lane], p_s);
            p_d = fmaf(g, Wd_p[k*30 + lane], p_d);
        }
        s0v[lane] = a_s;
        s0p[lane] = p_s;
        f4[3][lane] = a_d;
        f4[0][lane] = p_d;
        f4[2][lane] = y30_g[(size_t)b * 30 + lane];
    }
    __syncthreads();

    if (lane < 30) {
        float v_s = bsp[lane], p_s = bsp[lane];
        for (int j = 0; j < 30; ++j) {
            float wj = Wsp[j*30 + lane];
            v_s = fmaf(s0v[j], wj, v_s);
            p_s = fmaf(s0p[j], wj, p_s);
        }
        float h1 = v_s, h2 = p_s, h12 = h1 + h2;
        float m1 = fmaxf(h12, fmaxf(h1, h2));
        float lse1 = m1 + logf(2.f*expf(h12 - m1) + expf(h1 - m1) + expf(h2 - m1));
        float m2 = fmaxf(0.f, fmaxf(h1, h2));
        float lse2 = m2 + logf(2.f*expf(-m2) + expf(h1 - m2) + expf(h2 - m2));
        f4[1][lane] = pf ? (lse1 - lse2) : h2;
    }
    __syncthreads();

    #pragma unroll 1
    for (int t = 0; t < 4; ++t) {
        #pragma unroll 1
        for (int c0 = 0; c0 < 3; ++c0) {
            int c = c0 * 64 + lane;
            float a = ba[c];
            for (int j = 0; j < 30; ++j)
                a = fmaf(f4[t][j], Wa[j*192 + c], a);
            qk[t][c] = a;
        }
    }
    __syncthreads();

    if (lane < 32) {
        float q0 = qk[0][lane], q1 = qk[1][lane], q2 = qk[2][lane], q3 = qk[3][lane];
        qm[lane] = pf ? (q0 + q1 + q2 + q3) * 0.25f
                      : (q0 + q1 + q2) * (1.f / 3.f);
    }
    __syncthreads();

    if (lane < 16) {
        int n = lane >> 2, t = lane & 3;
        float a = 0.f;
        const float* kp = &qk[t][64 + 32*n];
        for (int d = 0; d < 32; ++d) a = fmaf(kp[d], qm[d], a);
        a *= 0.17677669529663687f;
        if (t == 3 && pf == 0) a = -INFINITY;
        lg[n][t] = a;
    }
    __syncthreads();

    if (lane < 4) {
        float l0 = lg[lane][0], l1 = lg[lane][1], l2 = lg[lane][2], l3 = lg[lane][3];
        float m = fmaxf(fmaxf(l0, l1), fmaxf(l2, l3));
        float e0 = expf(l0 - m), e1 = expf(l1 - m), e2 = expf(l2 - m);
        float e3 = expf(l3 - m);
        float s = e0 + e1 + e2 + e3;
        wsm[lane][0] = e0 / s; wsm[lane][1] = e1 / s;
        wsm[lane][2] = e2 / s; wsm[lane][3] = e3 / s;
    }
    __syncthreads();

    #pragma unroll
    for (int r = 0; r < 2; ++r) {
        int n = (lane >> 5) + 2 * r, d = lane & 31;
        float a = 0.f;
        #pragma unroll
        for (int t = 0; t < 4; ++t) a = fmaf(wsm[n][t], qk[t][32 + d], a);
        ffl[n][d] = a;
    }
    __syncthreads();

    if (lane < 4) {
        float a = bf[lane];
        for (int d = 0; d < 32; ++d) a = fmaf(ffl[lane][d], Wf[d*4 + lane], a);
        out[(size_t)b * 4 + lane] = a;
    }
}

// ---------------------------------------------------------------------------
extern "C" void kernel_launch(void* const* d_in, const int* in_sizes, int n_in,
                              void* d_out, int out_size, void* d_ws, size_t ws_size,
                              hipStream_t stream)
{
    const int*   pairs = (const int*)  d_in[0];
    const float* S_V   = (const float*)d_in[1];
    const float* S_P   = (const float*)d_in[2];
    const float* S_P1  = (const float*)d_in[3];
    const float* Wc_v  = (const float*)d_in[4];
    const float* bc_v  = (const float*)d_in[5];
    const float* Ws_v  = (const float*)d_in[6];
    const float* bs_v  = (const float*)d_in[7];
    const float* Wd_v  = (const float*)d_in[8];
    const float* bd_v  = (const float*)d_in[9];
    const float* Wc_p  = (const float*)d_in[10];
    const float* bc_p  = (const float*)d_in[11];
    const float* Ws_p  = (const float*)d_in[12];
    const float* bs_p  = (const float*)d_in[13];
    const float* Wd_p  = (const float*)d_in[14];
    const float* bd_p  = (const float*)d_in[15];
    const float* Wsp   = (const float*)d_in[16];
    const float* bsp   = (const float*)d_in[17];
    const float* W1    = (const float*)d_in[18];
    const float* b1    = (const float*)d_in[19];
    const float* W2    = (const float*)d_in[20];
    const float* b2    = (const float*)d_in[21];
    const float* Wa    = (const float*)d_in[22];
    const float* ba    = (const float*)d_in[23];
    const float* Wf    = (const float*)d_in[24];
    const float* bf    = (const float*)d_in[25];
    float* out = (float*)d_out;

    // ws: h_v[B][64] | h_p[B][64] | y30[B][30] | frags (26 x 64 x 16B)
    float* ws  = (float*)d_ws;
    float* h_v = ws;
    float* h_p = ws + (size_t)B_ * 64;
    float* y30 = ws + (size_t)2 * B_ * 64;
    unsigned short* Frag = (unsigned short*)(ws + (size_t)2 * B_ * 64 + (size_t)B_ * 30);

    prep_frags<<<7, 256, 0, stream>>>(W2, Wc_v, Wc_p, W1, bc_v, bc_p, b1, Frag);
    encode_mfma_kernel<<<dim3(B_, 2), 512, 0, stream>>>(
        S_V, S_P, Frag, h_v, h_p);
    phys_kernel<<<B_, 512, 0, stream>>>(S_P1, Frag, b2, y30);
    head_kernel<<<B_, 64, 0, stream>>>(pairs, h_v, h_p, y30,
                                       Ws_v, bs_v, Wd_v, bd_v,
                                       Ws_p, bs_p, Wd_p, bd_p,
                                       Wsp, bsp, Wa, ba, Wf, bf, out);
}

// Round 4
// 289.514 us; speedup vs baseline: 1.3914x; 1.0856x over previous
//
#include <hip/hip_runtime.h>
#include <math.h>

#define B_   4096

typedef __attribute__((ext_vector_type(8)))  short bf16x8;   // 8 bf16 = 4 VGPR
typedef __attribute__((ext_vector_type(4)))  float f32x4;
typedef __attribute__((ext_vector_type(16))) float f32x16;

// packed f32->bf16 RNE, single VALU instruction (gfx950; no builtin — T12 recipe)
__device__ __forceinline__ unsigned int pk2(float a, float b) {
    unsigned int r;
    asm("v_cvt_pk_bf16_f32 %0, %1, %2" : "=v"(r) : "v"(a), "v"(b));
    return r;
}
__device__ __forceinline__ f32x16 zero16() {
    f32x16 z;
    #pragma unroll
    for (int i = 0; i < 16; ++i) z[i] = 0.f;
    return z;
}
// max of 4 consecutive regs (pool4 along the register/time axis) — tree, depth 2
__device__ __forceinline__ float max4(float a, float b, float c, float d) {
    return fmaxf(fmaxf(a, b), fmaxf(c, d));
}
// tree-sum of relu over 16 regs (short dependency chain)
__device__ __forceinline__ float sumrelu16(const f32x16& y) {
    float t0 = (fmaxf(y[0], 0.f) + fmaxf(y[1], 0.f)) + (fmaxf(y[2], 0.f) + fmaxf(y[3], 0.f));
    float t1 = (fmaxf(y[4], 0.f) + fmaxf(y[5], 0.f)) + (fmaxf(y[6], 0.f) + fmaxf(y[7], 0.f));
    float t2 = (fmaxf(y[8], 0.f) + fmaxf(y[9], 0.f)) + (fmaxf(y[10],0.f) + fmaxf(y[11],0.f));
    float t3 = (fmaxf(y[12],0.f) + fmaxf(y[13],0.f)) + (fmaxf(y[14],0.f) + fmaxf(y[15],0.f));
    return (t0 + t1) + (t2 + t3);
}

// ---------------------------------------------------------------------------
// prep: all MFMA fragments (26 x 64 lanes x 16B). Bias folded at k=15 for
// the 32x32x16 conv fragments (signal supplies a ones-column there).
// A and B fragment lane-layouts are identical on gfx950, so these bytes
// serve as EITHER operand.
//  e 0..19 : phys phase-2 (16x16x32), e=(kk*2+Ks)*2+ftile
//  e 20..23: encoder conv (32x32x16), e-20=enc*2+mt; j<9 W, j==15 bias
//  e 24..25: phys phase-1 (32x32x16), mt=e-24;       j<15 W, j==15 bias
// ---------------------------------------------------------------------------
__global__ void prep_frags(const float* __restrict__ W2,
                           const float* __restrict__ Wc_v,
                           const float* __restrict__ Wc_p,
                           const float* __restrict__ W1,
                           const float* __restrict__ bc_v,
                           const float* __restrict__ bc_p,
                           const float* __restrict__ b1,
                           unsigned short* __restrict__ ws_frag)
{
    int gid = blockIdx.x * 256 + threadIdx.x;
    if (gid >= 26 * 64) return;
    int lane = gid & 63, e = gid >> 6;
    unsigned int w[4];
    if (e < 20) {
        int ft = e & 1, Ks = (e >> 1) & 1, kk = e >> 2;
        int m = lane & 15, kg = lane >> 4;
        int f = ft * 16 + m;
        #pragma unroll
        for (int p = 0; p < 4; ++p) {
            int i0 = Ks * 32 + kg * 8 + 2 * p;
            float v0 = (f < 30) ? W2[f * 320 + i0 * 5 + kk] : 0.f;
            float v1 = (f < 30) ? W2[f * 320 + (i0 + 1) * 5 + kk] : 0.f;
            w[p] = pk2(v0, v1);
        }
    } else if (e < 24) {
        int e2 = e - 20, enc = e2 >> 1, mt = e2 & 1;
        const float* Wc = enc ? Wc_p : Wc_v;
        const float* bc = enc ? bc_p : bc_v;
        int c = mt * 32 + (lane & 31), kg = lane >> 5;
        #pragma unroll
        for (int p = 0; p < 4; ++p) {
            int j0 = kg * 8 + 2 * p, j1 = j0 + 1;
            float v0 = (j0 < 9) ? Wc[c * 9 + (j0 % 3) * 3 + (j0 / 3)] : 0.f;
            float v1 = (j1 < 9) ? Wc[c * 9 + (j1 % 3) * 3 + (j1 / 3)]
                                : (j1 == 15 ? bc[c] : 0.f);
            w[p] = pk2(v0, v1);
        }
    } else {
        int mt = e - 24;
        int c = mt * 32 + (lane & 31), kg = lane >> 5;
        #pragma unroll
        for (int p = 0; p < 4; ++p) {
            int j0 = kg * 8 + 2 * p, j1 = j0 + 1;
            float v0 = (j0 < 15) ? W1[c * 15 + (j0 % 3) * 5 + (j0 / 3)] : 0.f;
            float v1 = (j1 < 15) ? W1[c * 15 + (j1 % 3) * 5 + (j1 / 3)]
                                 : (j1 == 15 ? b1[c] : 0.f);
            w[p] = pk2(v0, v1);
        }
    }
    ((uint4*)ws_frag)[gid] = make_uint4(w[0], w[1], w[2], w[3]);
}

// ---------------------------------------------------------------------------
// Encoder: conv(3->64,K=3)+bias (in-K) + ReLU + mean via 32x32x16 MFMA.
// Signal staged to LDS cooperatively (coalesced float2), B-fragments built
// from LDS (conflict-free: bank 3n%32 bijective). 512 threads, 8 waves.
// ---------------------------------------------------------------------------
__global__ __launch_bounds__(512, 8) void encode_mfma_kernel(
    const float* __restrict__ S_V, const float* __restrict__ S_P,
    const unsigned short* __restrict__ Frag,
    float* __restrict__ hv, float* __restrict__ hp)
{
    __shared__ __align__(16) float sig[3072];   // 12 KB
    __shared__ float red[2][8][64];             // 4 KB
    const int enc = blockIdx.y;
    const float* __restrict__ S = enc ? S_P : S_V;
    float* hout = enc ? hp : hv;
    const int b = blockIdx.x, tid = threadIdx.x;
    const int lane = tid & 63, wv = tid >> 6;
    const int n = lane & 31, kg = lane >> 5;
    const float* __restrict__ xb = S + (size_t)b * 3072;

    // stage signal: 1536 float2, fully coalesced
    #pragma unroll
    for (int i = 0; i < 3; ++i) {
        int idx = tid + i * 512;
        ((float2*)sig)[idx] = ((const float2*)xb)[idx];
    }
    const bf16x8* fr = (const bf16x8*)Frag;
    bf16x8 Bf0 = fr[(20 + enc * 2) * 64 + lane];   // weights ch 0..31 (as B)
    bf16x8 Bf1 = fr[(21 + enc * 2) * 64 + lane];   // weights ch 32..63
    __syncthreads();

    float s0 = 0.f, s1 = 0.f;

    #pragma unroll 1
    for (int nt = wv; nt < 32; nt += 8) {
        const int t = nt * 32 + n;                 // n = time row of A
        union { unsigned int u[4]; bf16x8 v; } bb;
        bb.u[0] = bb.u[1] = bb.u[2] = bb.u[3] = 0u;
        if (t < 1022) {
            const float* xp = sig + 3 * t;
            if (kg == 0) {          // k=0..7 -> x[3t..3t+7]
                bb.u[0] = pk2(xp[0], xp[1]); bb.u[1] = pk2(xp[2], xp[3]);
                bb.u[2] = pk2(xp[4], xp[5]); bb.u[3] = pk2(xp[6], xp[7]);
            } else {                // k=8 -> x[3t+8]; k=15 -> 1.0 (bias col)
                bb.u[0] = pk2(xp[8], 0.f);
                bb.u[3] = 0x3F800000u;   // packed (0.0, 1.0) in bf16
            }
        }
        f32x16 y0 = __builtin_amdgcn_mfma_f32_32x32x16_bf16(bb.v, Bf0, zero16(), 0, 0, 0);
        f32x16 y1 = __builtin_amdgcn_mfma_f32_32x32x16_bf16(bb.v, Bf1, zero16(), 0, 0, 0);
        s0 += sumrelu16(y0);       // lane holds channel n   (16 time rows)
        s1 += sumrelu16(y1);       // lane holds channel n+32
    }

    red[0][wv][lane] = s0;
    red[1][wv][lane] = s1;
    __syncthreads();
    if (tid < 64) {                 // tid = channel c
        int half = tid >> 5, c32 = tid & 31;
        float s = 0.f;
        #pragma unroll
        for (int w = 0; w < 8; ++w)
            s += red[half][w][c32] + red[half][w][c32 + 32];
        hout[(size_t)b * 64 + tid] = s * (1.0f / 1022.0f);
    }
}

// ---------------------------------------------------------------------------
// Physical model, time on register axis. 512 threads (8 waves), 3 blocks/CU
// (LDS ~50 KB). Phase 0: stage signal to LDS with coalesced float2 loads
// (kills the 12B-stride scattered global loads that saturated L1 MSHRs).
// Phase 1: B-fragments built from LDS (ds_read2, 2-way banks = free);
// pool4 = max of 4 consecutive acc regs; bf16 scalar stores to p1T.
// Phase 2: 5 shifted 16x16x32 MFMAs; pool4 on regs; parallel 8-way reduce.
// ---------------------------------------------------------------------------
#define P1TS 72
__global__ __launch_bounds__(512, 6) void phys_kernel(
    const float* __restrict__ S, const unsigned short* __restrict__ Frag,
    const float* __restrict__ b2, float* __restrict__ y30)
{
    __shared__ __align__(16) float sig[3104];                  // 12.1 KB (+pad)
    __shared__ __align__(16) unsigned short p1T[260 * P1TS];   // 37.4 KB
    __shared__ float part[8][32];                              // 1 KB
    float* ymat = (float*)p1T;                                  // overlay, phase-2 epilogue
    const int b = blockIdx.x, tid = threadIdx.x;
    const int lane = tid & 63, wv = tid >> 6;                   // wv 0..7
    const float* __restrict__ xb = S + (size_t)b * 3072;
    const bf16x8* fr = (const bf16x8*)Frag;

    // stage signal: 1536 float2 coalesced + zero pad (reads up to sig[3083])
    #pragma unroll
    for (int i = 0; i < 3; ++i) {
        int idx = tid + i * 512;
        ((float2*)sig)[idx] = ((const float2*)xb)[idx];
    }
    if (tid < 16) ((float2*)sig)[1536 + tid] = make_float2(0.f, 0.f);
    // zero pad rows tp=255..259 (read via kk shifts in phase 2)
    if (tid < 180) ((unsigned int*)(p1T + 255 * P1TS))[tid] = 0u;
    __syncthreads();

    // ---- phase 1 ----
    {
        const int n = lane & 31, kg2 = lane >> 5;
        bf16x8 W10 = fr[24 * 64 + lane];    // weights ch 0..31  (as B)
        bf16x8 W11 = fr[25 * 64 + lane];    // weights ch 32..63
        #pragma unroll 1
        for (int ntl = wv; ntl < 32; ntl += 8) {
            const int t = ntl * 32 + n;      // n = time row of A
            const float* xp = sig + 3 * t + kg2 * 8;
            // t=1020..1023 read zero pad; results discarded via t4<255
            union { unsigned int u[4]; bf16x8 v; } bb;
            bb.u[0] = pk2(xp[0], xp[1]);
            bb.u[1] = pk2(xp[2], xp[3]);
            bb.u[2] = pk2(xp[4], xp[5]);
            bb.u[3] = pk2(xp[6], kg2 ? 1.0f : xp[7]);
            // D[t][c]: lane = channel (col), regs = 16 time rows
            f32x16 y0 = __builtin_amdgcn_mfma_f32_32x32x16_bf16(bb.v, W10, zero16(), 0, 0, 0);
            #pragma unroll
            for (int g4 = 0; g4 < 4; ++g4) {
                const int t4 = ntl * 8 + 2 * g4 + kg2;
                if (t4 < 255) {
                    float p0 = max4(y0[4*g4+0], y0[4*g4+1], y0[4*g4+2], y0[4*g4+3]);
                    p1T[t4 * P1TS + n] = (unsigned short)pk2(p0, p0);
                }
            }
            f32x16 y1 = __builtin_amdgcn_mfma_f32_32x32x16_bf16(bb.v, W11, zero16(), 0, 0, 0);
            #pragma unroll
            for (int g4 = 0; g4 < 4; ++g4) {
                const int t4 = ntl * 8 + 2 * g4 + kg2;
                if (t4 < 255) {
                    float p1 = max4(y1[4*g4+0], y1[4*g4+1], y1[4*g4+2], y1[4*g4+3]);
                    p1T[t4 * P1TS + n + 32] = (unsigned short)pk2(p1, p1);
                }
            }
        }
    }
    __syncthreads();

    // ---- phase 2 ----
    const int m_ = lane & 15, kg16 = lane >> 4;
    f32x4 acc[2][2];
    #pragma unroll
    for (int q = 0; q < 2; ++q) {
        acc[q][0] = (f32x4){0.f, 0.f, 0.f, 0.f};
        acc[q][1] = (f32x4){0.f, 0.f, 0.f, 0.f};
    }
    #pragma unroll 1
    for (int Ks = 0; Ks < 2; ++Ks) {
        bf16x8 Wf[10];
        #pragma unroll
        for (int kk = 0; kk < 5; ++kk) {
            Wf[kk * 2]     = fr[((kk * 2 + Ks) * 2) * 64 + lane];
            Wf[kk * 2 + 1] = fr[((kk * 2 + Ks) * 2 + 1) * 64 + lane];
        }
        #pragma unroll
        for (int kk = 0; kk < 5; ++kk) {
            #pragma unroll
            for (int q = 0; q < 2; ++q) {
                const int row = wv * 32 + q * 16 + m_ + kk;   // m_ = time row of A
                const bf16x8 Pf = *(const bf16x8*)(p1T + row * P1TS + Ks * 32 + kg16 * 8);
                // D[t][f]: lane&15 = feature (col), kg16*4+reg = time row
                acc[q][0] = __builtin_amdgcn_mfma_f32_16x16x32_bf16(Pf, Wf[kk*2],   acc[q][0], 0, 0, 0);
                acc[q][1] = __builtin_amdgcn_mfma_f32_16x16x32_bf16(Pf, Wf[kk*2+1], acc[q][1], 0, 0, 0);
            }
        }
    }
    __syncthreads();    // all p1T reads done; safe to overlay ymat

    // epilogue: lane's 4 acc regs = rows {kg16*4..+3} = one pool4 group
    #pragma unroll
    for (int q = 0; q < 2; ++q) {
        #pragma unroll
        for (int ft = 0; ft < 2; ++ft) {
            f32x4 av = acc[q][ft];
            float p = max4(av[0], av[1], av[2], av[3]);
            int n4 = wv * 8 + q * 4 + kg16;
            ymat[n4 * 36 + ft * 16 + m_] = p;   // m_ = feature here
        }
    }
    __syncthreads();
    // parallel reduce: 8 partial sums per feature, then 8-add combine
    if (tid < 256) {
        int w8 = tid >> 5, f = tid & 31;
        if (f < 30) {
            float s = 0.f;
            #pragma unroll 2
            for (int r = w8; r < 62; r += 8) s += ymat[r * 36 + f];
            part[w8][f] = s;
        }
    }
    __syncthreads();
    if (tid < 30) {
        float s = 0.f;
        #pragma unroll
        for (int w8 = 0; w8 < 8; ++w8) s += part[w8][tid];
        y30[(size_t)b * 30 + tid] = s * (1.0f / 62.0f) + b2[tid];
    }
}

// ---------------------------------------------------------------------------
// Heads + LSE soft-OR fusion + masked 4-token attention. 1 wave per b.
// qkv projection: t-loop unrolled -> 4-way ILP + Wa-load reuse across tokens.
// ---------------------------------------------------------------------------
__global__ __launch_bounds__(64) void head_kernel(
    const int* __restrict__ pairs,
    const float* __restrict__ hv_g, const float* __restrict__ hp_g,
    const float* __restrict__ y30_g,
    const float* __restrict__ Ws_v, const float* __restrict__ bs_v,
    const float* __restrict__ Wd_v, const float* __restrict__ bd_v,
    const float* __restrict__ Ws_p, const float* __restrict__ bs_p,
    const float* __restrict__ Wd_p, const float* __restrict__ bd_p,
    const float* __restrict__ Wsp, const float* __restrict__ bsp,
    const float* __restrict__ Wa,  const float* __restrict__ ba,
    const float* __restrict__ Wf,  const float* __restrict__ bf,
    float* __restrict__ out)
{
    __shared__ float hv[64], hp[64];
    __shared__ float s0v[32], s0p[32];
    __shared__ float f4[4][32];
    __shared__ float qk[4][192];
    __shared__ float qm[32];
    __shared__ float lg[4][4];
    __shared__ float wsm[4][4];
    __shared__ float ffl[4][32];
    const int b = blockIdx.x;
    const int lane = threadIdx.x;
    const int pf = pairs[b];

    hv[lane] = hv_g[(size_t)b * 64 + lane];
    hp[lane] = hp_g[(size_t)b * 64 + lane];
    __syncthreads();

    if (lane < 30) {
        float a_s = bs_v[lane], a_d = bd_v[lane];
        float p_s = bs_p[lane], p_d = bd_p[lane];
        for (int k = 0; k < 64; ++k) {
            float h = hv[k], g = hp[k];
            a_s = fmaf(h, Ws_v[k*30 + lane], a_s);
            a_d = fmaf(h, Wd_v[k*30 + lane], a_d);
            p_s = fmaf(g, Ws_p[k*30 + lane], p_s);
            p_d = fmaf(g, Wd_p[k*30 + lane], p_d);
        }
        s0v[lane] = a_s;
        s0p[lane] = p_s;
        f4[3][lane] = a_d;
        f4[0][lane] = p_d;
        f4[2][lane] = y30_g[(size_t)b * 30 + lane];
    }
    __syncthreads();

    if (lane < 30) {
        float v_s = bsp[lane], p_s = bsp[lane];
        for (int j = 0; j < 30; ++j) {
            float wj = Wsp[j*30 + lane];
            v_s = fmaf(s0v[j], wj, v_s);
            p_s = fmaf(s0p[j], wj, p_s);
        }
        float h1 = v_s, h2 = p_s, h12 = h1 + h2;
        float m1 = fmaxf(h12, fmaxf(h1, h2));
        float lse1 = m1 + logf(2.f*expf(h12 - m1) + expf(h1 - m1) + expf(h2 - m1));
        float m2 = fmaxf(0.f, fmaxf(h1, h2));
        float lse2 = m2 + logf(2.f*expf(-m2) + expf(h1 - m2) + expf(h2 - m2));
        f4[1][lane] = pf ? (lse1 - lse2) : h2;
    }
    __syncthreads();

    #pragma unroll 1
    for (int c0 = 0; c0 < 3; ++c0) {
        int c = c0 * 64 + lane;
        float a0 = ba[c], a1 = a0, a2 = a0, a3 = a0;
        for (int j = 0; j < 30; ++j) {
            float w = Wa[j*192 + c];            // shared across the 4 tokens
            a0 = fmaf(f4[0][j], w, a0);
            a1 = fmaf(f4[1][j], w, a1);
            a2 = fmaf(f4[2][j], w, a2);
            a3 = fmaf(f4[3][j], w, a3);
        }
        qk[0][c] = a0; qk[1][c] = a1; qk[2][c] = a2; qk[3][c] = a3;
    }
    __syncthreads();

    if (lane < 32) {
        float q0 = qk[0][lane], q1 = qk[1][lane], q2 = qk[2][lane], q3 = qk[3][lane];
        qm[lane] = pf ? (q0 + q1 + q2 + q3) * 0.25f
                      : (q0 + q1 + q2) * (1.f / 3.f);
    }
    __syncthreads();

    if (lane < 16) {
        int n = lane >> 2, t = lane & 3;
        float a = 0.f;
        const float* kp = &qk[t][64 + 32*n];
        for (int d = 0; d < 32; ++d) a = fmaf(kp[d], qm[d], a);
        a *= 0.17677669529663687f;
        if (t == 3 && pf == 0) a = -INFINITY;
        lg[n][t] = a;
    }
    __syncthreads();

    if (lane < 4) {
        float l0 = lg[lane][0], l1 = lg[lane][1], l2 = lg[lane][2], l3 = lg[lane][3];
        float m = fmaxf(fmaxf(l0, l1), fmaxf(l2, l3));
        float e0 = expf(l0 - m), e1 = expf(l1 - m), e2 = expf(l2 - m);
        float e3 = expf(l3 - m);
        float s = e0 + e1 + e2 + e3;
        wsm[lane][0] = e0 / s; wsm[lane][1] = e1 / s;
        wsm[lane][2] = e2 / s; wsm[lane][3] = e3 / s;
    }
    __syncthreads();

    #pragma unroll
    for (int r = 0; r < 2; ++r) {
        int n = (lane >> 5) + 2 * r, d = lane & 31;
        float a = 0.f;
        #pragma unroll
        for (int t = 0; t < 4; ++t) a = fmaf(wsm[n][t], qk[t][32 + d], a);
        ffl[n][d] = a;
    }
    __syncthreads();

    if (lane < 4) {
        float a = bf[lane];
        for (int d = 0; d < 32; ++d) a = fmaf(ffl[lane][d], Wf[d*4 + lane], a);
        out[(size_t)b * 4 + lane] = a;
    }
}

// ---------------------------------------------------------------------------
extern "C" void kernel_launch(void* const* d_in, const int* in_sizes, int n_in,
                              void* d_out, int out_size, void* d_ws, size_t ws_size,
                              hipStream_t stream)
{
    const int*   pairs = (const int*)  d_in[0];
    const float* S_V   = (const float*)d_in[1];
    const float* S_P   = (const float*)d_in[2];
    const float* S_P1  = (const float*)d_in[3];
    const float* Wc_v  = (const float*)d_in[4];
    const float* bc_v  = (const float*)d_in[5];
    const float* Ws_v  = (const float*)d_in[6];
    const float* bs_v  = (const float*)d_in[7];
    const float* Wd_v  = (const float*)d_in[8];
    const float* bd_v  = (const float*)d_in[9];
    const float* Wc_p  = (const float*)d_in[10];
    const float* bc_p  = (const float*)d_in[11];
    const float* Ws_p  = (const float*)d_in[12];
    const float* bs_p  = (const float*)d_in[13];
    const float* Wd_p  = (const float*)d_in[14];
    const float* bd_p  = (const float*)d_in[15];
    const float* Wsp   = (const float*)d_in[16];
    const float* bsp   = (const float*)d_in[17];
    const float* W1    = (const float*)d_in[18];
    const float* b1    = (const float*)d_in[19];
    const float* W2    = (const float*)d_in[20];
    const float* b2    = (const float*)d_in[21];
    const float* Wa    = (const float*)d_in[22];
    const float* ba    = (const float*)d_in[23];
    const float* Wf    = (const float*)d_in[24];
    const float* bf    = (const float*)d_in[25];
    float* out = (float*)d_out;

    // ws: h_v[B][64] | h_p[B][64] | y30[B][30] | frags (26 x 64 x 16B)
    float* ws  = (float*)d_ws;
    float* h_v = ws;
    float* h_p = ws + (size_t)B_ * 64;
    float* y30 = ws + (size_t)2 * B_ * 64;
    unsigned short* Frag = (unsigned short*)(ws + (size_t)2 * B_ * 64 + (size_t)B_ * 30);

    prep_frags<<<7, 256, 0, stream>>>(W2, Wc_v, Wc_p, W1, bc_v, bc_p, b1, Frag);
    encode_mfma_kernel<<<dim3(B_, 2), 512, 0, stream>>>(
        S_V, S_P, Frag, h_v, h_p);
    phys_kernel<<<B_, 512, 0, stream>>>(S_P1, Frag, b2, y30);
    head_kernel<<<B_, 64, 0, stream>>>(pairs, h_v, h_p, y30,
                                       Ws_v, bs_v, Wd_v, bd_v,
                                       Ws_p, bs_p, Wd_p, bd_p,
                                       Wsp, bsp, Wa, ba, Wf, bf, out);
}

// Round 5
// 286.906 us; speedup vs baseline: 1.4040x; 1.0091x over previous
//
#include <hip/hip_runtime.h>
#include <math.h>

#define B_   4096

typedef __attribute__((ext_vector_type(8)))  short bf16x8;   // 8 bf16 = 4 VGPR
typedef __attribute__((ext_vector_type(4)))  float f32x4;
typedef __attribute__((ext_vector_type(16))) float f32x16;

// packed f32->bf16 RNE, single VALU instruction (gfx950; no builtin — T12 recipe)
__device__ __forceinline__ unsigned int pk2(float a, float b) {
    unsigned int r;
    asm("v_cvt_pk_bf16_f32 %0, %1, %2" : "=v"(r) : "v"(a), "v"(b));
    return r;
}
__device__ __forceinline__ f32x16 zero16() {
    f32x16 z;
    #pragma unroll
    for (int i = 0; i < 16; ++i) z[i] = 0.f;
    return z;
}
// max of 4 consecutive regs (pool4 along the register/time axis) — tree, depth 2
__device__ __forceinline__ float max4(float a, float b, float c, float d) {
    return fmaxf(fmaxf(a, b), fmaxf(c, d));
}

// ---------------------------------------------------------------------------
// prep: all MFMA fragments (26 x 64 lanes x 16B). Bias folded at k=15 for
// the 32x32x16 conv fragments (signal supplies a ones-column there).
// A and B fragment lane-layouts are identical on gfx950, so these bytes
// serve as EITHER operand.
//  e 0..19 : phys phase-2 (16x16x32), e=(kk*2+Ks)*2+ftile
//  e 20..23: encoder conv (32x32x16), e-20=enc*2+mt; j<9 W, j==15 bias
//  e 24..25: phys phase-1 (32x32x16), mt=e-24;       j<15 W, j==15 bias
// ---------------------------------------------------------------------------
__global__ void prep_frags(const float* __restrict__ W2,
                           const float* __restrict__ Wc_v,
                           const float* __restrict__ Wc_p,
                           const float* __restrict__ W1,
                           const float* __restrict__ bc_v,
                           const float* __restrict__ bc_p,
                           const float* __restrict__ b1,
                           unsigned short* __restrict__ ws_frag)
{
    int gid = blockIdx.x * 256 + threadIdx.x;
    if (gid >= 26 * 64) return;
    int lane = gid & 63, e = gid >> 6;
    unsigned int w[4];
    if (e < 20) {
        int ft = e & 1, Ks = (e >> 1) & 1, kk = e >> 2;
        int m = lane & 15, kg = lane >> 4;
        int f = ft * 16 + m;
        #pragma unroll
        for (int p = 0; p < 4; ++p) {
            int i0 = Ks * 32 + kg * 8 + 2 * p;
            float v0 = (f < 30) ? W2[f * 320 + i0 * 5 + kk] : 0.f;
            float v1 = (f < 30) ? W2[f * 320 + (i0 + 1) * 5 + kk] : 0.f;
            w[p] = pk2(v0, v1);
        }
    } else if (e < 24) {
        int e2 = e - 20, enc = e2 >> 1, mt = e2 & 1;
        const float* Wc = enc ? Wc_p : Wc_v;
        const float* bc = enc ? bc_p : bc_v;
        int c = mt * 32 + (lane & 31), kg = lane >> 5;
        #pragma unroll
        for (int p = 0; p < 4; ++p) {
            int j0 = kg * 8 + 2 * p, j1 = j0 + 1;
            float v0 = (j0 < 9) ? Wc[c * 9 + (j0 % 3) * 3 + (j0 / 3)] : 0.f;
            float v1 = (j1 < 9) ? Wc[c * 9 + (j1 % 3) * 3 + (j1 / 3)]
                                : (j1 == 15 ? bc[c] : 0.f);
            w[p] = pk2(v0, v1);
        }
    } else {
        int mt = e - 24;
        int c = mt * 32 + (lane & 31), kg = lane >> 5;
        #pragma unroll
        for (int p = 0; p < 4; ++p) {
            int j0 = kg * 8 + 2 * p, j1 = j0 + 1;
            float v0 = (j0 < 15) ? W1[c * 15 + (j0 % 3) * 5 + (j0 / 3)] : 0.f;
            float v1 = (j1 < 15) ? W1[c * 15 + (j1 % 3) * 5 + (j1 / 3)]
                                 : (j1 == 15 ? b1[c] : 0.f);
            w[p] = pk2(v0, v1);
        }
    }
    ((uint4*)ws_frag)[gid] = make_uint4(w[0], w[1], w[2], w[3]);
}

// ---------------------------------------------------------------------------
// MERGED encode + phys. grid = 3*B_, type = bx%3 (0: enc S_V, 1: enc S_P,
// 2: phys S_P1) so adjacent blocks mix memory-heavy and LDS/VALU-heavy work
// on the same CUs, and two full inter-kernel pipeline drains are removed.
//
// Encode: conv(3->64,K=3)+bias+ReLU+mean. Compute-MFMA puts time on the
// register axis; the time-SUM is done by a second ones-A MFMA (C-accumulated
// across iterations) instead of a 31-op VALU add-tree:
//   lane n supplies k=0..7 from y-regs (times (k&3)+8*(k>>2)+4*kg),
//   lane n+32 supplies k=8..15 — one sum-MFMA reduces 16 distinct times.
// Phys: identical to R4 (verified): LDS-staged signal, pool4 on regs.
// LDS: phys needs 50.9 KB -> 3 blocks/CU; launch_bounds (512,6) leaves
// ample VGPR (no AGPR<->VGPR shuttling of the f32x16 outputs).
// ---------------------------------------------------------------------------
#define P1TS 72
__global__ __launch_bounds__(512, 6) void enc_phys_kernel(
    const float* __restrict__ S_V, const float* __restrict__ S_P,
    const float* __restrict__ S_P1,
    const unsigned short* __restrict__ Frag,
    const float* __restrict__ b2,
    float* __restrict__ hv, float* __restrict__ hp, float* __restrict__ y30)
{
    __shared__ __align__(16) char smraw[12416 + 37440 + 1024];   // 50.9 KB
    float* sig = (float*)smraw;                                  // [3104]
    unsigned short* p1T = (unsigned short*)(smraw + 12416);      // phys [260*72]
    float* part = (float*)(smraw + 12416 + 37440);               // phys [8][32]
    float* red  = (float*)(smraw + 12416);                       // enc overlay [2][8][32]
    float* ymat = (float*)p1T;                                   // phys epilogue overlay

    const int bx = blockIdx.x;
    const int type = bx % 3;          // 0,1: encoder; 2: phys
    const int b = bx / 3;
    const int tid = threadIdx.x;
    const int lane = tid & 63, wv = tid >> 6;                    // wv 0..7
    const bf16x8* fr = (const bf16x8*)Frag;

    if (type < 2) {
        // =================== encoder path ===================
        const float* __restrict__ xb = (type ? S_P : S_V) + (size_t)b * 3072;
        float* hout = type ? hp : hv;
        const int n = lane & 31, kg = lane >> 5;

        #pragma unroll
        for (int i = 0; i < 3; ++i) {
            int idx = tid + i * 512;
            ((float2*)sig)[idx] = ((const float2*)xb)[idx];
        }
        bf16x8 Bf0 = fr[(20 + type * 2) * 64 + lane];   // weights ch 0..31
        bf16x8 Bf1 = fr[(21 + type * 2) * 64 + lane];   // weights ch 32..63
        union { unsigned int u[4]; bf16x8 v; } ones;
        ones.u[0] = ones.u[1] = ones.u[2] = ones.u[3] = 0x3F803F80u;  // 8x bf16 1.0
        __syncthreads();

        f32x16 sum0 = zero16(), sum1 = zero16();

        #pragma unroll 1
        for (int nt = wv; nt < 32; nt += 8) {
            const int t = nt * 32 + n;                 // n = time row of A
            union { unsigned int u[4]; bf16x8 v; } bb;
            bb.u[0] = bb.u[1] = bb.u[2] = bb.u[3] = 0u;
            if (t < 1022) {
                const float* xp = sig + 3 * t;
                if (kg == 0) {          // k=0..7 -> x[3t..3t+7]
                    bb.u[0] = pk2(xp[0], xp[1]); bb.u[1] = pk2(xp[2], xp[3]);
                    bb.u[2] = pk2(xp[4], xp[5]); bb.u[3] = pk2(xp[6], xp[7]);
                } else {                // k=8 -> x[3t+8]; k=15 -> 1.0 (bias col)
                    bb.u[0] = pk2(xp[8], 0.f);
                    bb.u[3] = 0x3F800000u;   // packed (0.0, 1.0) in bf16
                }
            }
            f32x16 y0 = __builtin_amdgcn_mfma_f32_32x32x16_bf16(bb.v, Bf0, zero16(), 0, 0, 0);
            f32x16 y1 = __builtin_amdgcn_mfma_f32_32x32x16_bf16(bb.v, Bf1, zero16(), 0, 0, 0);
            // relu -> bf16 pack -> ones-A MFMA time-sum (C-accumulated)
            union { unsigned int u[4]; bf16x8 v; } pa, pb;
            #pragma unroll
            for (int p = 0; p < 4; ++p) {
                pa.u[p] = pk2(fmaxf(y0[2*p],   0.f), fmaxf(y0[2*p+1],   0.f));
                pb.u[p] = pk2(fmaxf(y0[8+2*p], 0.f), fmaxf(y0[8+2*p+1], 0.f));
            }
            sum0 = __builtin_amdgcn_mfma_f32_32x32x16_bf16(ones.v, pa.v, sum0, 0, 0, 0);
            sum0 = __builtin_amdgcn_mfma_f32_32x32x16_bf16(ones.v, pb.v, sum0, 0, 0, 0);
            #pragma unroll
            for (int p = 0; p < 4; ++p) {
                pa.u[p] = pk2(fmaxf(y1[2*p],   0.f), fmaxf(y1[2*p+1],   0.f));
                pb.u[p] = pk2(fmaxf(y1[8+2*p], 0.f), fmaxf(y1[8+2*p+1], 0.f));
            }
            sum1 = __builtin_amdgcn_mfma_f32_32x32x16_bf16(ones.v, pa.v, sum1, 0, 0, 0);
            sum1 = __builtin_amdgcn_mfma_f32_32x32x16_bf16(ones.v, pb.v, sum1, 0, 0, 0);
        }
        // every row of the ones-A product equals the column sum; read reg 0
        __syncthreads();            // sig reads done; red overlays p1T region anyway
        if (lane < 32) {
            red[(0 * 8 + wv) * 32 + n] = sum0[0];
            red[(1 * 8 + wv) * 32 + n] = sum1[0];
        }
        __syncthreads();
        if (tid < 64) {             // tid = channel c
            int half = tid >> 5, c32 = tid & 31;
            float s = 0.f;
            #pragma unroll
            for (int w = 0; w < 8; ++w) s += red[(half * 8 + w) * 32 + c32];
            hout[(size_t)b * 64 + tid] = s * (1.0f / 1022.0f);
        }
        return;
    }

    // =================== phys path (verified R4 structure) ===================
    const float* __restrict__ xb = S_P1 + (size_t)b * 3072;

    #pragma unroll
    for (int i = 0; i < 3; ++i) {
        int idx = tid + i * 512;
        ((float2*)sig)[idx] = ((const float2*)xb)[idx];
    }
    if (tid < 16) ((float2*)sig)[1536 + tid] = make_float2(0.f, 0.f);
    if (tid < 180) ((unsigned int*)(p1T + 255 * P1TS))[tid] = 0u;
    __syncthreads();

    // ---- phase 1 ----
    {
        const int n = lane & 31, kg2 = lane >> 5;
        bf16x8 W10 = fr[24 * 64 + lane];    // weights ch 0..31  (as B)
        bf16x8 W11 = fr[25 * 64 + lane];    // weights ch 32..63
        #pragma unroll 1
        for (int ntl = wv; ntl < 32; ntl += 8) {
            const int t = ntl * 32 + n;      // n = time row of A
            const float* xp = sig + 3 * t + kg2 * 8;
            union { unsigned int u[4]; bf16x8 v; } bb;
            bb.u[0] = pk2(xp[0], xp[1]);
            bb.u[1] = pk2(xp[2], xp[3]);
            bb.u[2] = pk2(xp[4], xp[5]);
            bb.u[3] = pk2(xp[6], kg2 ? 1.0f : xp[7]);
            f32x16 y0 = __builtin_amdgcn_mfma_f32_32x32x16_bf16(bb.v, W10, zero16(), 0, 0, 0);
            #pragma unroll
            for (int g4 = 0; g4 < 4; ++g4) {
                const int t4 = ntl * 8 + 2 * g4 + kg2;
                if (t4 < 255) {
                    float p0 = max4(y0[4*g4+0], y0[4*g4+1], y0[4*g4+2], y0[4*g4+3]);
                    p1T[t4 * P1TS + n] = (unsigned short)pk2(p0, p0);
                }
            }
            f32x16 y1 = __builtin_amdgcn_mfma_f32_32x32x16_bf16(bb.v, W11, zero16(), 0, 0, 0);
            #pragma unroll
            for (int g4 = 0; g4 < 4; ++g4) {
                const int t4 = ntl * 8 + 2 * g4 + kg2;
                if (t4 < 255) {
                    float p1 = max4(y1[4*g4+0], y1[4*g4+1], y1[4*g4+2], y1[4*g4+3]);
                    p1T[t4 * P1TS + n + 32] = (unsigned short)pk2(p1, p1);
                }
            }
        }
    }
    __syncthreads();

    // ---- phase 2 ----
    const int m_ = lane & 15, kg16 = lane >> 4;
    f32x4 acc[2][2];
    #pragma unroll
    for (int q = 0; q < 2; ++q) {
        acc[q][0] = (f32x4){0.f, 0.f, 0.f, 0.f};
        acc[q][1] = (f32x4){0.f, 0.f, 0.f, 0.f};
    }
    #pragma unroll 1
    for (int Ks = 0; Ks < 2; ++Ks) {
        bf16x8 Wf[10];
        #pragma unroll
        for (int kk = 0; kk < 5; ++kk) {
            Wf[kk * 2]     = fr[((kk * 2 + Ks) * 2) * 64 + lane];
            Wf[kk * 2 + 1] = fr[((kk * 2 + Ks) * 2 + 1) * 64 + lane];
        }
        #pragma unroll
        for (int kk = 0; kk < 5; ++kk) {
            #pragma unroll
            for (int q = 0; q < 2; ++q) {
                const int row = wv * 32 + q * 16 + m_ + kk;   // m_ = time row of A
                const bf16x8 Pf = *(const bf16x8*)(p1T + row * P1TS + Ks * 32 + kg16 * 8);
                acc[q][0] = __builtin_amdgcn_mfma_f32_16x16x32_bf16(Pf, Wf[kk*2],   acc[q][0], 0, 0, 0);
                acc[q][1] = __builtin_amdgcn_mfma_f32_16x16x32_bf16(Pf, Wf[kk*2+1], acc[q][1], 0, 0, 0);
            }
        }
    }
    __syncthreads();    // all p1T reads done; safe to overlay ymat

    #pragma unroll
    for (int q = 0; q < 2; ++q) {
        #pragma unroll
        for (int ft = 0; ft < 2; ++ft) {
            f32x4 av = acc[q][ft];
            float p = max4(av[0], av[1], av[2], av[3]);
            int n4 = wv * 8 + q * 4 + kg16;
            ymat[n4 * 36 + ft * 16 + m_] = p;   // m_ = feature here
        }
    }
    __syncthreads();
    if (tid < 256) {
        int w8 = tid >> 5, f = tid & 31;
        if (f < 30) {
            float s = 0.f;
            #pragma unroll 2
            for (int r = w8; r < 62; r += 8) s += ymat[r * 36 + f];
            part[w8 * 32 + f] = s;
        }
    }
    __syncthreads();
    if (tid < 30) {
        float s = 0.f;
        #pragma unroll
        for (int w8 = 0; w8 < 8; ++w8) s += part[w8 * 32 + tid];
        y30[(size_t)b * 30 + tid] = s * (1.0f / 62.0f) + b2[tid];
    }
}

// ---------------------------------------------------------------------------
// Heads + LSE soft-OR fusion + masked 4-token attention. 1 wave per b.
// qkv projection: t-loop unrolled -> 4-way ILP + Wa-load reuse across tokens.
// ---------------------------------------------------------------------------
__global__ __launch_bounds__(64) void head_kernel(
    const int* __restrict__ pairs,
    const float* __restrict__ hv_g, const float* __restrict__ hp_g,
    const float* __restrict__ y30_g,
    const float* __restrict__ Ws_v, const float* __restrict__ bs_v,
    const float* __restrict__ Wd_v, const float* __restrict__ bd_v,
    const float* __restrict__ Ws_p, const float* __restrict__ bs_p,
    const float* __restrict__ Wd_p, const float* __restrict__ bd_p,
    const float* __restrict__ Wsp, const float* __restrict__ bsp,
    const float* __restrict__ Wa,  const float* __restrict__ ba,
    const float* __restrict__ Wf,  const float* __restrict__ bf,
    float* __restrict__ out)
{
    __shared__ float hv[64], hp[64];
    __shared__ float s0v[32], s0p[32];
    __shared__ float f4[4][32];
    __shared__ float qk[4][192];
    __shared__ float qm[32];
    __shared__ float lg[4][4];
    __shared__ float wsm[4][4];
    __shared__ float ffl[4][32];
    const int b = blockIdx.x;
    const int lane = threadIdx.x;
    const int pf = pairs[b];

    hv[lane] = hv_g[(size_t)b * 64 + lane];
    hp[lane] = hp_g[(size_t)b * 64 + lane];
    __syncthreads();

    if (lane < 30) {
        float a_s = bs_v[lane], a_d = bd_v[lane];
        float p_s = bs_p[lane], p_d = bd_p[lane];
        for (int k = 0; k < 64; ++k) {
            float h = hv[k], g = hp[k];
            a_s = fmaf(h, Ws_v[k*30 + lane], a_s);
            a_d = fmaf(h, Wd_v[k*30 + lane], a_d);
            p_s = fmaf(g, Ws_p[k*30 + lane], p_s);
            p_d = fmaf(g, Wd_p[k*30 + lane], p_d);
        }
        s0v[lane] = a_s;
        s0p[lane] = p_s;
        f4[3][lane] = a_d;
        f4[0][lane] = p_d;
        f4[2][lane] = y30_g[(size_t)b * 30 + lane];
    }
    __syncthreads();

    if (lane < 30) {
        float v_s = bsp[lane], p_s = bsp[lane];
        for (int j = 0; j < 30; ++j) {
            float wj = Wsp[j*30 + lane];
            v_s = fmaf(s0v[j], wj, v_s);
            p_s = fmaf(s0p[j], wj, p_s);
        }
        float h1 = v_s, h2 = p_s, h12 = h1 + h2;
        float m1 = fmaxf(h12, fmaxf(h1, h2));
        float lse1 = m1 + logf(2.f*expf(h12 - m1) + expf(h1 - m1) + expf(h2 - m1));
        float m2 = fmaxf(0.f, fmaxf(h1, h2));
        float lse2 = m2 + logf(2.f*expf(-m2) + expf(h1 - m2) + expf(h2 - m2));
        f4[1][lane] = pf ? (lse1 - lse2) : h2;
    }
    __syncthreads();

    #pragma unroll 1
    for (int c0 = 0; c0 < 3; ++c0) {
        int c = c0 * 64 + lane;
        float a0 = ba[c], a1 = a0, a2 = a0, a3 = a0;
        for (int j = 0; j < 30; ++j) {
            float w = Wa[j*192 + c];            // shared across the 4 tokens
            a0 = fmaf(f4[0][j], w, a0);
            a1 = fmaf(f4[1][j], w, a1);
            a2 = fmaf(f4[2][j], w, a2);
            a3 = fmaf(f4[3][j], w, a3);
        }
        qk[0][c] = a0; qk[1][c] = a1; qk[2][c] = a2; qk[3][c] = a3;
    }
    __syncthreads();

    if (lane < 32) {
        float q0 = qk[0][lane], q1 = qk[1][lane], q2 = qk[2][lane], q3 = qk[3][lane];
        qm[lane] = pf ? (q0 + q1 + q2 + q3) * 0.25f
                      : (q0 + q1 + q2) * (1.f / 3.f);
    }
    __syncthreads();

    if (lane < 16) {
        int n = lane >> 2, t = lane & 3;
        float a = 0.f;
        const float* kp = &qk[t][64 + 32*n];
        for (int d = 0; d < 32; ++d) a = fmaf(kp[d], qm[d], a);
        a *= 0.17677669529663687f;
        if (t == 3 && pf == 0) a = -INFINITY;
        lg[n][t] = a;
    }
    __syncthreads();

    if (lane < 4) {
        float l0 = lg[lane][0], l1 = lg[lane][1], l2 = lg[lane][2], l3 = lg[lane][3];
        float m = fmaxf(fmaxf(l0, l1), fmaxf(l2, l3));
        float e0 = expf(l0 - m), e1 = expf(l1 - m), e2 = expf(l2 - m);
        float e3 = expf(l3 - m);
        float s = e0 + e1 + e2 + e3;
        wsm[lane][0] = e0 / s; wsm[lane][1] = e1 / s;
        wsm[lane][2] = e2 / s; wsm[lane][3] = e3 / s;
    }
    __syncthreads();

    #pragma unroll
    for (int r = 0; r < 2; ++r) {
        int n = (lane >> 5) + 2 * r, d = lane & 31;
        float a = 0.f;
        #pragma unroll
        for (int t = 0; t < 4; ++t) a = fmaf(wsm[n][t], qk[t][32 + d], a);
        ffl[n][d] = a;
    }
    __syncthreads();

    if (lane < 4) {
        float a = bf[lane];
        for (int d = 0; d < 32; ++d) a = fmaf(ffl[lane][d], Wf[d*4 + lane], a);
        out[(size_t)b * 4 + lane] = a;
    }
}

// ---------------------------------------------------------------------------
extern "C" void kernel_launch(void* const* d_in, const int* in_sizes, int n_in,
                              void* d_out, int out_size, void* d_ws, size_t ws_size,
                              hipStream_t stream)
{
    const int*   pairs = (const int*)  d_in[0];
    const float* S_V   = (const float*)d_in[1];
    const float* S_P   = (const float*)d_in[2];
    const float* S_P1  = (const float*)d_in[3];
    const float* Wc_v  = (const float*)d_in[4];
    const float* bc_v  = (const float*)d_in[5];
    const float* Ws_v  = (const float*)d_in[6];
    const float* bs_v  = (const float*)d_in[7];
    const float* Wd_v  = (const float*)d_in[8];
    const float* bd_v  = (const float*)d_in[9];
    const float* Wc_p  = (const float*)d_in[10];
    const float* bc_p  = (const float*)d_in[11];
    const float* Ws_p  = (const float*)d_in[12];
    const float* bs_p  = (const float*)d_in[13];
    const float* Wd_p  = (const float*)d_in[14];
    const float* bd_p  = (const float*)d_in[15];
    const float* Wsp   = (const float*)d_in[16];
    const float* bsp   = (const float*)d_in[17];
    const float* W1    = (const float*)d_in[18];
    const float* b1    = (const float*)d_in[19];
    const float* W2    = (const float*)d_in[20];
    const float* b2    = (const float*)d_in[21];
    const float* Wa    = (const float*)d_in[22];
    const float* ba    = (const float*)d_in[23];
    const float* Wf    = (const float*)d_in[24];
    const float* bf    = (const float*)d_in[25];
    float* out = (float*)d_out;

    // ws: h_v[B][64] | h_p[B][64] | y30[B][30] | frags (26 x 64 x 16B)
    float* ws  = (float*)d_ws;
    float* h_v = ws;
    float* h_p = ws + (size_t)B_ * 64;
    float* y30 = ws + (size_t)2 * B_ * 64;
    unsigned short* Frag = (unsigned short*)(ws + (size_t)2 * B_ * 64 + (size_t)B_ * 30);

    prep_frags<<<7, 256, 0, stream>>>(W2, Wc_v, Wc_p, W1, bc_v, bc_p, b1, Frag);
    enc_phys_kernel<<<3 * B_, 512, 0, stream>>>(
        S_V, S_P, S_P1, Frag, b2, h_v, h_p, y30);
    head_kernel<<<B_, 64, 0, stream>>>(pairs, h_v, h_p, y30,
                                       Ws_v, bs_v, Wd_v, bd_v,
                                       Ws_p, bs_p, Wd_p, bd_p,
                                       Wsp, bsp, Wa, ba, Wf, bf, out);
}

// Round 6
// 273.669 us; speedup vs baseline: 1.4719x; 1.0484x over previous
//
#include <hip/hip_runtime.h>
#include <math.h>

#define B_   4096
#define HB   16      // samples per head block

typedef __attribute__((ext_vector_type(8)))  short bf16x8;   // 8 bf16 = 4 VGPR
typedef __attribute__((ext_vector_type(4)))  float f32x4;
typedef __attribute__((ext_vector_type(16))) float f32x16;

// packed f32->bf16 RNE, single VALU instruction (gfx950; no builtin — T12 recipe)
__device__ __forceinline__ unsigned int pk2(float a, float b) {
    unsigned int r;
    asm("v_cvt_pk_bf16_f32 %0, %1, %2" : "=v"(r) : "v"(a), "v"(b));
    return r;
}
__device__ __forceinline__ f32x16 zero16() {
    f32x16 z;
    #pragma unroll
    for (int i = 0; i < 16; ++i) z[i] = 0.f;
    return z;
}
__device__ __forceinline__ float max4(float a, float b, float c, float d) {
    return fmaxf(fmaxf(a, b), fmaxf(c, d));
}
// quad (lanes t=0..3) all-reduce max / sum via DPP
__device__ __forceinline__ float maxq(float v) {
    int y1 = __builtin_amdgcn_update_dpp(0, __float_as_int(v), 0xB1, 0xF, 0xF, true);
    float v1 = fmaxf(v, __int_as_float(y1));
    int y2 = __builtin_amdgcn_update_dpp(0, __float_as_int(v1), 0x4E, 0xF, 0xF, true);
    return fmaxf(v1, __int_as_float(y2));
}
__device__ __forceinline__ float sumq(float v) {
    int y1 = __builtin_amdgcn_update_dpp(0, __float_as_int(v), 0xB1, 0xF, 0xF, true);
    float v1 = v + __int_as_float(y1);
    int y2 = __builtin_amdgcn_update_dpp(0, __float_as_int(v1), 0x4E, 0xF, 0xF, true);
    return v1 + __int_as_float(y2);
}

// ---------------------------------------------------------------------------
// prep: all MFMA fragments (56 x 64 lanes x 16B). A and B fragment lane
// layouts are identical on gfx950 (16x16x32: n=lane&15, k=(lane>>4)*8+j).
//  e 0..19 : phys phase-2 (16x16x32), e=(kk*2+Ks)*2+ftile
//  e 20..23: encoder conv (32x32x16), e-20=enc*2+mt; j<9 W, j==15 bias
//  e 24..25: phys phase-1 (32x32x16), mt=e-24;       j<15 W, j==15 bias
//  e 26..41: head stage-A [Ws|Wd] concat, K=64 N=64(o<60 valid):
//            e = 26 + side*8 + Kc*4 + ntile   (side 0=v, 1=p)
//  e 42..43: head Wsp, K=32 (k<30 W, k31 bsp), N=32 (o<30): e = 42+ntile
//  e 44..55: head Wa,  K=32 (k<30 W, k31 ba),  N=192:       e = 44+ntile
// ---------------------------------------------------------------------------
__global__ void prep_frags(const float* __restrict__ W2,
                           const float* __restrict__ Wc_v,
                           const float* __restrict__ Wc_p,
                           const float* __restrict__ W1,
                           const float* __restrict__ bc_v,
                           const float* __restrict__ bc_p,
                           const float* __restrict__ b1,
                           const float* __restrict__ Ws_v,
                           const float* __restrict__ Wd_v,
                           const float* __restrict__ Ws_p,
                           const float* __restrict__ Wd_p,
                           const float* __restrict__ Wsp,
                           const float* __restrict__ bsp,
                           const float* __restrict__ Wa,
                           const float* __restrict__ ba,
                           unsigned short* __restrict__ ws_frag)
{
    int gid = blockIdx.x * 256 + threadIdx.x;
    if (gid >= 56 * 64) return;
    int lane = gid & 63, e = gid >> 6;
    unsigned int w[4];
    if (e < 20) {
        int ft = e & 1, Ks = (e >> 1) & 1, kk = e >> 2;
        int m = lane & 15, kg = lane >> 4;
        int f = ft * 16 + m;
        #pragma unroll
        for (int p = 0; p < 4; ++p) {
            int i0 = Ks * 32 + kg * 8 + 2 * p;
            float v0 = (f < 30) ? W2[f * 320 + i0 * 5 + kk] : 0.f;
            float v1 = (f < 30) ? W2[f * 320 + (i0 + 1) * 5 + kk] : 0.f;
            w[p] = pk2(v0, v1);
        }
    } else if (e < 24) {
        int e2 = e - 20, enc = e2 >> 1, mt = e2 & 1;
        const float* Wc = enc ? Wc_p : Wc_v;
        const float* bc = enc ? bc_p : bc_v;
        int c = mt * 32 + (lane & 31), kg = lane >> 5;
        #pragma unroll
        for (int p = 0; p < 4; ++p) {
            int j0 = kg * 8 + 2 * p, j1 = j0 + 1;
            float v0 = (j0 < 9) ? Wc[c * 9 + (j0 % 3) * 3 + (j0 / 3)] : 0.f;
            float v1 = (j1 < 9) ? Wc[c * 9 + (j1 % 3) * 3 + (j1 / 3)]
                                : (j1 == 15 ? bc[c] : 0.f);
            w[p] = pk2(v0, v1);
        }
    } else if (e < 26) {
        int mt = e - 24;
        int c = mt * 32 + (lane & 31), kg = lane >> 5;
        #pragma unroll
        for (int p = 0; p < 4; ++p) {
            int j0 = kg * 8 + 2 * p, j1 = j0 + 1;
            float v0 = (j0 < 15) ? W1[c * 15 + (j0 % 3) * 5 + (j0 / 3)] : 0.f;
            float v1 = (j1 < 15) ? W1[c * 15 + (j1 % 3) * 5 + (j1 / 3)]
                                 : (j1 == 15 ? b1[c] : 0.f);
            w[p] = pk2(v0, v1);
        }
    } else if (e < 42) {
        int e2 = e - 26;
        int side = e2 >> 3, idx = e2 & 7;
        int Kc = idx >> 2, nt = idx & 3;
        const float* Ws = side ? Ws_p : Ws_v;
        const float* Wd = side ? Wd_p : Wd_v;
        int o = nt * 16 + (lane & 15), kg = lane >> 4;
        #pragma unroll
        for (int p = 0; p < 4; ++p) {
            int j0 = Kc * 32 + kg * 8 + 2 * p, j1 = j0 + 1;
            float v0 = (o < 30) ? Ws[j0 * 30 + o] : (o < 60 ? Wd[j0 * 30 + o - 30] : 0.f);
            float v1 = (o < 30) ? Ws[j1 * 30 + o] : (o < 60 ? Wd[j1 * 30 + o - 30] : 0.f);
            w[p] = pk2(v0, v1);
        }
    } else if (e < 44) {
        int nt = e - 42;
        int o = nt * 16 + (lane & 15), kg = lane >> 4;
        #pragma unroll
        for (int p = 0; p < 4; ++p) {
            int j0 = kg * 8 + 2 * p, j1 = j0 + 1;
            float v0 = 0.f, v1 = 0.f;
            if (o < 30) {
                v0 = (j0 < 30) ? Wsp[j0 * 30 + o] : (j0 == 31 ? bsp[o] : 0.f);
                v1 = (j1 < 30) ? Wsp[j1 * 30 + o] : (j1 == 31 ? bsp[o] : 0.f);
            }
            w[p] = pk2(v0, v1);
        }
    } else {
        int nt = e - 44;
        int c = nt * 16 + (lane & 15), kg = lane >> 4;
        #pragma unroll
        for (int p = 0; p < 4; ++p) {
            int j0 = kg * 8 + 2 * p, j1 = j0 + 1;
            float v0 = (j0 < 30) ? Wa[j0 * 192 + c] : (j0 == 31 ? ba[c] : 0.f);
            float v1 = (j1 < 30) ? Wa[j1 * 192 + c] : (j1 == 31 ? ba[c] : 0.f);
            w[p] = pk2(v0, v1);
        }
    }
    ((uint4*)ws_frag)[gid] = make_uint4(w[0], w[1], w[2], w[3]);
}

// ---------------------------------------------------------------------------
// MERGED encode + phys (unchanged from R5 — verified). grid = 3*B_,
// type = bx%3 (0: enc S_V, 1: enc S_P, 2: phys S_P1).
// ---------------------------------------------------------------------------
#define P1TS 72
__global__ __launch_bounds__(512, 6) void enc_phys_kernel(
    const float* __restrict__ S_V, const float* __restrict__ S_P,
    const float* __restrict__ S_P1,
    const unsigned short* __restrict__ Frag,
    const float* __restrict__ b2,
    float* __restrict__ hv, float* __restrict__ hp, float* __restrict__ y30)
{
    __shared__ __align__(16) char smraw[12416 + 37440 + 1024];   // 50.9 KB
    float* sig = (float*)smraw;                                  // [3104]
    unsigned short* p1T = (unsigned short*)(smraw + 12416);      // phys [260*72]
    float* part = (float*)(smraw + 12416 + 37440);               // phys [8][32]
    float* red  = (float*)(smraw + 12416);                       // enc overlay [2][8][32]
    float* ymat = (float*)p1T;                                   // phys epilogue overlay

    const int bx = blockIdx.x;
    const int type = bx % 3;          // 0,1: encoder; 2: phys
    const int b = bx / 3;
    const int tid = threadIdx.x;
    const int lane = tid & 63, wv = tid >> 6;                    // wv 0..7
    const bf16x8* fr = (const bf16x8*)Frag;

    if (type < 2) {
        // =================== encoder path ===================
        const float* __restrict__ xb = (type ? S_P : S_V) + (size_t)b * 3072;
        float* hout = type ? hp : hv;
        const int n = lane & 31, kg = lane >> 5;

        #pragma unroll
        for (int i = 0; i < 3; ++i) {
            int idx = tid + i * 512;
            ((float2*)sig)[idx] = ((const float2*)xb)[idx];
        }
        bf16x8 Bf0 = fr[(20 + type * 2) * 64 + lane];   // weights ch 0..31
        bf16x8 Bf1 = fr[(21 + type * 2) * 64 + lane];   // weights ch 32..63
        union { unsigned int u[4]; bf16x8 v; } ones;
        ones.u[0] = ones.u[1] = ones.u[2] = ones.u[3] = 0x3F803F80u;  // 8x bf16 1.0
        __syncthreads();

        f32x16 sum0 = zero16(), sum1 = zero16();

        #pragma unroll 1
        for (int nt = wv; nt < 32; nt += 8) {
            const int t = nt * 32 + n;                 // n = time row of A
            union { unsigned int u[4]; bf16x8 v; } bb;
            bb.u[0] = bb.u[1] = bb.u[2] = bb.u[3] = 0u;
            if (t < 1022) {
                const float* xp = sig + 3 * t;
                if (kg == 0) {          // k=0..7 -> x[3t..3t+7]
                    bb.u[0] = pk2(xp[0], xp[1]); bb.u[1] = pk2(xp[2], xp[3]);
                    bb.u[2] = pk2(xp[4], xp[5]); bb.u[3] = pk2(xp[6], xp[7]);
                } else {                // k=8 -> x[3t+8]; k=15 -> 1.0 (bias col)
                    bb.u[0] = pk2(xp[8], 0.f);
                    bb.u[3] = 0x3F800000u;   // packed (0.0, 1.0) in bf16
                }
            }
            f32x16 y0 = __builtin_amdgcn_mfma_f32_32x32x16_bf16(bb.v, Bf0, zero16(), 0, 0, 0);
            f32x16 y1 = __builtin_amdgcn_mfma_f32_32x32x16_bf16(bb.v, Bf1, zero16(), 0, 0, 0);
            union { unsigned int u[4]; bf16x8 v; } pa, pb;
            #pragma unroll
            for (int p = 0; p < 4; ++p) {
                pa.u[p] = pk2(fmaxf(y0[2*p],   0.f), fmaxf(y0[2*p+1],   0.f));
                pb.u[p] = pk2(fmaxf(y0[8+2*p], 0.f), fmaxf(y0[8+2*p+1], 0.f));
            }
            sum0 = __builtin_amdgcn_mfma_f32_32x32x16_bf16(ones.v, pa.v, sum0, 0, 0, 0);
            sum0 = __builtin_amdgcn_mfma_f32_32x32x16_bf16(ones.v, pb.v, sum0, 0, 0, 0);
            #pragma unroll
            for (int p = 0; p < 4; ++p) {
                pa.u[p] = pk2(fmaxf(y1[2*p],   0.f), fmaxf(y1[2*p+1],   0.f));
                pb.u[p] = pk2(fmaxf(y1[8+2*p], 0.f), fmaxf(y1[8+2*p+1], 0.f));
            }
            sum1 = __builtin_amdgcn_mfma_f32_32x32x16_bf16(ones.v, pa.v, sum1, 0, 0, 0);
            sum1 = __builtin_amdgcn_mfma_f32_32x32x16_bf16(ones.v, pb.v, sum1, 0, 0, 0);
        }
        __syncthreads();
        if (lane < 32) {
            red[(0 * 8 + wv) * 32 + n] = sum0[0];
            red[(1 * 8 + wv) * 32 + n] = sum1[0];
        }
        __syncthreads();
        if (tid < 64) {
            int half = tid >> 5, c32 = tid & 31;
            float s = 0.f;
            #pragma unroll
            for (int w = 0; w < 8; ++w) s += red[(half * 8 + w) * 32 + c32];
            hout[(size_t)b * 64 + tid] = s * (1.0f / 1022.0f);
        }
        return;
    }

    // =================== phys path ===================
    const float* __restrict__ xb = S_P1 + (size_t)b * 3072;

    #pragma unroll
    for (int i = 0; i < 3; ++i) {
        int idx = tid + i * 512;
        ((float2*)sig)[idx] = ((const float2*)xb)[idx];
    }
    if (tid < 16) ((float2*)sig)[1536 + tid] = make_float2(0.f, 0.f);
    if (tid < 180) ((unsigned int*)(p1T + 255 * P1TS))[tid] = 0u;
    __syncthreads();

    // ---- phase 1 ----
    {
        const int n = lane & 31, kg2 = lane >> 5;
        bf16x8 W10 = fr[24 * 64 + lane];
        bf16x8 W11 = fr[25 * 64 + lane];
        #pragma unroll 1
        for (int ntl = wv; ntl < 32; ntl += 8) {
            const int t = ntl * 32 + n;
            const float* xp = sig + 3 * t + kg2 * 8;
            union { unsigned int u[4]; bf16x8 v; } bb;
            bb.u[0] = pk2(xp[0], xp[1]);
            bb.u[1] = pk2(xp[2], xp[3]);
            bb.u[2] = pk2(xp[4], xp[5]);
            bb.u[3] = pk2(xp[6], kg2 ? 1.0f : xp[7]);
            f32x16 y0 = __builtin_amdgcn_mfma_f32_32x32x16_bf16(bb.v, W10, zero16(), 0, 0, 0);
            #pragma unroll
            for (int g4 = 0; g4 < 4; ++g4) {
                const int t4 = ntl * 8 + 2 * g4 + kg2;
                if (t4 < 255) {
                    float p0 = max4(y0[4*g4+0], y0[4*g4+1], y0[4*g4+2], y0[4*g4+3]);
                    p1T[t4 * P1TS + n] = (unsigned short)pk2(p0, p0);
                }
            }
            f32x16 y1 = __builtin_amdgcn_mfma_f32_32x32x16_bf16(bb.v, W11, zero16(), 0, 0, 0);
            #pragma unroll
            for (int g4 = 0; g4 < 4; ++g4) {
                const int t4 = ntl * 8 + 2 * g4 + kg2;
                if (t4 < 255) {
                    float p1 = max4(y1[4*g4+0], y1[4*g4+1], y1[4*g4+2], y1[4*g4+3]);
                    p1T[t4 * P1TS + n + 32] = (unsigned short)pk2(p1, p1);
                }
            }
        }
    }
    __syncthreads();

    // ---- phase 2 ----
    const int m_ = lane & 15, kg16 = lane >> 4;
    f32x4 acc[2][2];
    #pragma unroll
    for (int q = 0; q < 2; ++q) {
        acc[q][0] = (f32x4){0.f, 0.f, 0.f, 0.f};
        acc[q][1] = (f32x4){0.f, 0.f, 0.f, 0.f};
    }
    #pragma unroll 1
    for (int Ks = 0; Ks < 2; ++Ks) {
        bf16x8 Wf[10];
        #pragma unroll
        for (int kk = 0; kk < 5; ++kk) {
            Wf[kk * 2]     = fr[((kk * 2 + Ks) * 2) * 64 + lane];
            Wf[kk * 2 + 1] = fr[((kk * 2 + Ks) * 2 + 1) * 64 + lane];
        }
        #pragma unroll
        for (int kk = 0; kk < 5; ++kk) {
            #pragma unroll
            for (int q = 0; q < 2; ++q) {
                const int row = wv * 32 + q * 16 + m_ + kk;
                const bf16x8 Pf = *(const bf16x8*)(p1T + row * P1TS + Ks * 32 + kg16 * 8);
                acc[q][0] = __builtin_amdgcn_mfma_f32_16x16x32_bf16(Pf, Wf[kk*2],   acc[q][0], 0, 0, 0);
                acc[q][1] = __builtin_amdgcn_mfma_f32_16x16x32_bf16(Pf, Wf[kk*2+1], acc[q][1], 0, 0, 0);
            }
        }
    }
    __syncthreads();

    #pragma unroll
    for (int q = 0; q < 2; ++q) {
        #pragma unroll
        for (int ft = 0; ft < 2; ++ft) {
            f32x4 av = acc[q][ft];
            float p = max4(av[0], av[1], av[2], av[3]);
            int n4 = wv * 8 + q * 4 + kg16;
            ymat[n4 * 36 + ft * 16 + m_] = p;
        }
    }
    __syncthreads();
    if (tid < 256) {
        int w8 = tid >> 5, f = tid & 31;
        if (f < 30) {
            float s = 0.f;
            #pragma unroll 2
            for (int r = w8; r < 62; r += 8) s += ymat[r * 36 + f];
            part[w8 * 32 + f] = s;
        }
    }
    __syncthreads();
    if (tid < 30) {
        float s = 0.f;
        #pragma unroll
        for (int w8 = 0; w8 < 8; ++w8) s += part[w8 * 32 + tid];
        y30[(size_t)b * 30 + tid] = s * (1.0f / 62.0f) + b2[tid];
    }
}

// ---------------------------------------------------------------------------
// Head as batched MFMA GEMMs. Block = 16 samples, 256 threads (4 waves),
// grid = B/16 = 256. 16x16x32 MFMA convention (same as phys phase 2):
//   A: row = lane&15 (sample), k = (lane>>4)*8+j
//   B: col = lane&15 (output), same k          (prebuilt in prep_frags)
//   D: col = lane&15, row = (lane>>4)*4 + reg
// Stage A: [16,64]@[Ws|Wd] for v/p sides (bias added in epilogue).
// Stage B: [16,32]@Wsp (ones-col at k=31 -> +bsp) -> h1,h2 -> LSE feat_avg.
// Stage C: tok[t][16,32]@Wa (ones-col k=31 -> +ba), wave w = token t.
// Stage D: qm / logits (quad-DPP softmax over t) / weighted-V / Wf diag.
// ---------------------------------------------------------------------------
__global__ __launch_bounds__(256, 2) void head_kernel(
    const int* __restrict__ pairs,
    const float* __restrict__ hv_g, const float* __restrict__ hp_g,
    const float* __restrict__ y30_g,
    const unsigned short* __restrict__ Frag,
    const float* __restrict__ bs_v, const float* __restrict__ bd_v,
    const float* __restrict__ bs_p, const float* __restrict__ bd_p,
    const float* __restrict__ Wf,  const float* __restrict__ bf,
    float* __restrict__ out)
{
    __shared__ __align__(16) float vs_tmp[16][36], ps_tmp[16][36];
    __shared__ __align__(16) float h1l[16][36], h2l[16][36];
    __shared__ __align__(16) float tok[4][16][36];
    __shared__ __align__(16) float qkl[4 * 3144];      // t*3144 + s*196 + c
    __shared__ __align__(16) float qml[16][32];
    __shared__ float wsml[16][4][4];
    __shared__ int pfl[16];
    const int b0 = blockIdx.x * HB;
    const int tid = threadIdx.x, lane = tid & 63, wv = tid >> 6;
    const bf16x8* fr = (const bf16x8*)Frag;
    const int sA = lane & 15, kgA = lane >> 4;
    union U { unsigned int u[4]; bf16x8 v; };

    // pads (k=30 -> 0, k=31 -> 1.0 ones/bias column), pf, tok[2]=y30
    if (tid < 16) {
        pfl[tid] = pairs[b0 + tid];
        vs_tmp[tid][30] = 0.f; vs_tmp[tid][31] = 1.0f;
        ps_tmp[tid][30] = 0.f; ps_tmp[tid][31] = 1.0f;
        #pragma unroll
        for (int t = 0; t < 4; ++t) { tok[t][tid][30] = 0.f; tok[t][tid][31] = 1.0f; }
    }
    #pragma unroll
    for (int i = 0; i < 2; ++i) {
        int idx = tid + i * 256;
        int s = idx >> 5, o = idx & 31;
        if (o < 30) tok[2][s][o] = y30_g[(size_t)(b0 + s) * 30 + o];
    }

    // ---- stage A: hv@[Ws_v|Wd_v], hp@[Ws_p|Wd_p]  (K=64, N-tile = wv) ----
    U Av0, Av1, Ap0, Ap1;
    {
        const float* hvp = hv_g + (size_t)(b0 + sA) * 64 + kgA * 8;
        const float* hpp = hp_g + (size_t)(b0 + sA) * 64 + kgA * 8;
        float4 x0 = *(const float4*)(hvp),      x1 = *(const float4*)(hvp + 4);
        float4 x2 = *(const float4*)(hvp + 32), x3 = *(const float4*)(hvp + 36);
        Av0.u[0] = pk2(x0.x, x0.y); Av0.u[1] = pk2(x0.z, x0.w);
        Av0.u[2] = pk2(x1.x, x1.y); Av0.u[3] = pk2(x1.z, x1.w);
        Av1.u[0] = pk2(x2.x, x2.y); Av1.u[1] = pk2(x2.z, x2.w);
        Av1.u[2] = pk2(x3.x, x3.y); Av1.u[3] = pk2(x3.z, x3.w);
        float4 y0 = *(const float4*)(hpp),      y1 = *(const float4*)(hpp + 4);
        float4 y2 = *(const float4*)(hpp + 32), y3 = *(const float4*)(hpp + 36);
        Ap0.u[0] = pk2(y0.x, y0.y); Ap0.u[1] = pk2(y0.z, y0.w);
        Ap0.u[2] = pk2(y1.x, y1.y); Ap0.u[3] = pk2(y1.z, y1.w);
        Ap1.u[0] = pk2(y2.x, y2.y); Ap1.u[1] = pk2(y2.z, y2.w);
        Ap1.u[2] = pk2(y3.x, y3.y); Ap1.u[3] = pk2(y3.z, y3.w);
    }
    {
        f32x4 accv = (f32x4){0.f,0.f,0.f,0.f}, accp = (f32x4){0.f,0.f,0.f,0.f};
        accv = __builtin_amdgcn_mfma_f32_16x16x32_bf16(Av0.v, fr[(26 + wv) * 64 + lane], accv, 0, 0, 0);
        accv = __builtin_amdgcn_mfma_f32_16x16x32_bf16(Av1.v, fr[(30 + wv) * 64 + lane], accv, 0, 0, 0);
        accp = __builtin_amdgcn_mfma_f32_16x16x32_bf16(Ap0.v, fr[(34 + wv) * 64 + lane], accp, 0, 0, 0);
        accp = __builtin_amdgcn_mfma_f32_16x16x32_bf16(Ap1.v, fr[(38 + wv) * 64 + lane], accp, 0, 0, 0);
        int oD = wv * 16 + sA;
        bool lo = oD < 30, hi = (oD >= 30) && (oD < 60);
        float bv = 0.f, bp = 0.f;
        if (lo) { bv = bs_v[oD]; bp = bs_p[oD]; }
        else if (hi) { bv = bd_v[oD - 30]; bp = bd_p[oD - 30]; }
        #pragma unroll
        for (int r = 0; r < 4; ++r) {
            int s = kgA * 4 + r;
            if (lo)      { vs_tmp[s][oD] = accv[r] + bv;  ps_tmp[s][oD] = accp[r] + bp; }
            else if (hi) { tok[3][s][oD-30] = accv[r] + bv; tok[0][s][oD-30] = accp[r] + bp; }
        }
    }
    __syncthreads();

    // ---- stage B: vs@Wsp, ps@Wsp (K=32 w/ ones-col; job = wave) ----
    {
        int side = wv >> 1, nt = wv & 1;
        const float (*src)[36] = side ? ps_tmp : vs_tmp;
        const float* ap = &src[sA][kgA * 8];
        float4 x0 = *(const float4*)ap, x1 = *(const float4*)(ap + 4);
        U A;
        A.u[0] = pk2(x0.x, x0.y); A.u[1] = pk2(x0.z, x0.w);
        A.u[2] = pk2(x1.x, x1.y); A.u[3] = pk2(x1.z, x1.w);
        f32x4 acc = (f32x4){0.f,0.f,0.f,0.f};
        acc = __builtin_amdgcn_mfma_f32_16x16x32_bf16(A.v, fr[(42 + nt) * 64 + lane], acc, 0, 0, 0);
        int oD = nt * 16 + sA;
        if (oD < 30) {
            float (*dst)[36] = side ? h2l : h1l;
            #pragma unroll
            for (int r = 0; r < 4; ++r) dst[kgA * 4 + r][oD] = acc[r];
        }
    }
    __syncthreads();

    // ---- LSE soft-OR fusion -> tok[1] ----
    #pragma unroll
    for (int i = 0; i < 2; ++i) {
        int idx = tid + i * 256;
        int s = idx >> 5, o = idx & 31;
        if (o < 30) {
            float h1 = h1l[s][o], h2 = h2l[s][o], h12 = h1 + h2;
            float m1 = fmaxf(h12, fmaxf(h1, h2));
            float lse1 = m1 + logf(2.f*expf(h12 - m1) + expf(h1 - m1) + expf(h2 - m1));
            float m2 = fmaxf(0.f, fmaxf(h1, h2));
            float lse2 = m2 + logf(2.f*expf(-m2) + expf(h1 - m2) + expf(h2 - m2));
            tok[1][s][o] = pfl[s] ? (lse1 - lse2) : h2;
        }
    }
    __syncthreads();

    // ---- stage C: tok[t]@Wa -> qk  (wave = token t, 12 N-tiles) ----
    {
        const float* ap = &tok[wv][sA][kgA * 8];
        float4 x0 = *(const float4*)ap, x1 = *(const float4*)(ap + 4);
        U A;
        A.u[0] = pk2(x0.x, x0.y); A.u[1] = pk2(x0.z, x0.w);
        A.u[2] = pk2(x1.x, x1.y); A.u[3] = pk2(x1.z, x1.w);
        #pragma unroll
        for (int nt = 0; nt < 12; ++nt) {
            f32x4 acc = (f32x4){0.f,0.f,0.f,0.f};
            acc = __builtin_amdgcn_mfma_f32_16x16x32_bf16(A.v, fr[(44 + nt) * 64 + lane], acc, 0, 0, 0);
            int c = nt * 16 + sA;
            #pragma unroll
            for (int r = 0; r < 4; ++r)
                qkl[wv * 3144 + (kgA * 4 + r) * 196 + c] = acc[r];
        }
    }
    __syncthreads();

    // ---- stage D ----
    // q_mean
    #pragma unroll
    for (int i = 0; i < 2; ++i) {
        int idx = tid + i * 256;
        int s = idx >> 5, d = idx & 31;
        float q0 = qkl[0*3144 + s*196 + d], q1 = qkl[1*3144 + s*196 + d];
        float q2 = qkl[2*3144 + s*196 + d], q3 = qkl[3*3144 + s*196 + d];
        qml[s][d] = pfl[s] ? (q0 + q1 + q2 + q3) * 0.25f
                           : (q0 + q1 + q2) * (1.f / 3.f);
    }
    __syncthreads();
    // logits + softmax over t (t lives in the quad -> DPP reduce)
    {
        int s = tid >> 4, n = (tid >> 2) & 3, t = tid & 3;
        const float4* kp = (const float4*)&qkl[t*3144 + s*196 + 64 + 32*n];
        const float4* qp = (const float4*)&qml[s][0];
        float a = 0.f;
        #pragma unroll
        for (int d4 = 0; d4 < 8; ++d4) {
            float4 k4 = kp[d4], q4 = qp[d4];
            a += k4.x*q4.x + k4.y*q4.y + k4.z*q4.z + k4.w*q4.w;
        }
        a *= 0.17677669529663687f;
        if (t == 3 && pfl[s] == 0) a = -INFINITY;
        float m = maxq(a);
        float e = expf(a - m);
        float ssum = sumq(e);
        wsml[s][n][t] = e / ssum;
    }
    __syncthreads();
    // weighted V + Wf diagonal
    if (tid < 64) {
        int s = tid >> 2, n = tid & 3;
        float w0 = wsml[s][n][0], w1 = wsml[s][n][1];
        float w2 = wsml[s][n][2], w3 = wsml[s][n][3];
        const float4* v0 = (const float4*)&qkl[0*3144 + s*196 + 32];
        const float4* v1 = (const float4*)&qkl[1*3144 + s*196 + 32];
        const float4* v2 = (const float4*)&qkl[2*3144 + s*196 + 32];
        const float4* v3 = (const float4*)&qkl[3*3144 + s*196 + 32];
        float acc = bf[n];
        #pragma unroll
        for (int d4 = 0; d4 < 8; ++d4) {
            float4 a0 = v0[d4], a1 = v1[d4], a2 = v2[d4], a3 = v3[d4];
            int d = d4 * 4;
            float f0 = w0*a0.x + w1*a1.x + w2*a2.x + w3*a3.x;
            float f1 = w0*a0.y + w1*a1.y + w2*a2.y + w3*a3.y;
            float f2 = w0*a0.z + w1*a1.z + w2*a2.z + w3*a3.z;
            float f3 = w0*a0.w + w1*a1.w + w2*a2.w + w3*a3.w;
            acc += f0 * Wf[d*4 + n]     + f1 * Wf[(d+1)*4 + n]
                 + f2 * Wf[(d+2)*4 + n] + f3 * Wf[(d+3)*4 + n];
        }
        out[(size_t)(b0 + s) * 4 + n] = acc;
    }
}

// ---------------------------------------------------------------------------
extern "C" void kernel_launch(void* const* d_in, const int* in_sizes, int n_in,
                              void* d_out, int out_size, void* d_ws, size_t ws_size,
                              hipStream_t stream)
{
    const int*   pairs = (const int*)  d_in[0];
    const float* S_V   = (const float*)d_in[1];
    const float* S_P   = (const float*)d_in[2];
    const float* S_P1  = (const float*)d_in[3];
    const float* Wc_v  = (const float*)d_in[4];
    const float* bc_v  = (const float*)d_in[5];
    const float* Ws_v  = (const float*)d_in[6];
    const float* bs_v  = (const float*)d_in[7];
    const float* Wd_v  = (const float*)d_in[8];
    const float* bd_v  = (const float*)d_in[9];
    const float* Wc_p  = (const float*)d_in[10];
    const float* bc_p  = (const float*)d_in[11];
    const float* Ws_p  = (const float*)d_in[12];
    const float* bs_p  = (const float*)d_in[13];
    const float* Wd_p  = (const float*)d_in[14];
    const float* bd_p  = (const float*)d_in[15];
    const float* Wsp   = (const float*)d_in[16];
    const float* bsp   = (const float*)d_in[17];
    const float* W1    = (const float*)d_in[18];
    const float* b1    = (const float*)d_in[19];
    const float* W2    = (const float*)d_in[20];
    const float* b2    = (const float*)d_in[21];
    const float* Wa    = (const float*)d_in[22];
    const float* ba    = (const float*)d_in[23];
    const float* Wf    = (const float*)d_in[24];
    const float* bf    = (const float*)d_in[25];
    float* out = (float*)d_out;

    // ws: h_v[B][64] | h_p[B][64] | y30[B][30] | frags (56 x 64 x 16B)
    float* ws  = (float*)d_ws;
    float* h_v = ws;
    float* h_p = ws + (size_t)B_ * 64;
    float* y30 = ws + (size_t)2 * B_ * 64;
    unsigned short* Frag = (unsigned short*)(ws + (size_t)2 * B_ * 64 + (size_t)B_ * 30);

    prep_frags<<<14, 256, 0, stream>>>(W2, Wc_v, Wc_p, W1, bc_v, bc_p, b1,
                                       Ws_v, Wd_v, Ws_p, Wd_p, Wsp, bsp, Wa, ba,
                                       Frag);
    enc_phys_kernel<<<3 * B_, 512, 0, stream>>>(
        S_V, S_P, S_P1, Frag, b2, h_v, h_p, y30);
    head_kernel<<<B_ / HB, 256, 0, stream>>>(
        pairs, h_v, h_p, y30, Frag,
        bs_v, bd_v, bs_p, bd_p, Wf, bf, out);
}

// Round 7
// 271.934 us; speedup vs baseline: 1.4813x; 1.0064x over previous
//
#include <hip/hip_runtime.h>
#include <math.h>

#define B_   4096
#define HB   16      // samples per head block

typedef __attribute__((ext_vector_type(8)))  short bf16x8;   // 8 bf16 = 4 VGPR
typedef __attribute__((ext_vector_type(4)))  float f32x4;
typedef __attribute__((ext_vector_type(16))) float f32x16;

// packed f32->bf16 RNE, single VALU instruction (gfx950; no builtin — T12 recipe)
__device__ __forceinline__ unsigned int pk2(float a, float b) {
    unsigned int r;
    asm("v_cvt_pk_bf16_f32 %0, %1, %2" : "=v"(r) : "v"(a), "v"(b));
    return r;
}
__device__ __forceinline__ f32x16 zero16() {
    f32x16 z;
    #pragma unroll
    for (int i = 0; i < 16; ++i) z[i] = 0.f;
    return z;
}
__device__ __forceinline__ float max4(float a, float b, float c, float d) {
    return fmaxf(fmaxf(a, b), fmaxf(c, d));
}
// quad (lanes t=0..3) all-reduce max / sum via DPP
__device__ __forceinline__ float maxq(float v) {
    int y1 = __builtin_amdgcn_update_dpp(0, __float_as_int(v), 0xB1, 0xF, 0xF, true);
    float v1 = fmaxf(v, __int_as_float(y1));
    int y2 = __builtin_amdgcn_update_dpp(0, __float_as_int(v1), 0x4E, 0xF, 0xF, true);
    return fmaxf(v1, __int_as_float(y2));
}
__device__ __forceinline__ float sumq(float v) {
    int y1 = __builtin_amdgcn_update_dpp(0, __float_as_int(v), 0xB1, 0xF, 0xF, true);
    float v1 = v + __int_as_float(y1);
    int y2 = __builtin_amdgcn_update_dpp(0, __float_as_int(v1), 0x4E, 0xF, 0xF, true);
    return v1 + __int_as_float(y2);
}

// ---------------------------------------------------------------------------
// prep: all MFMA fragments (56 x 64 lanes x 16B). A and B fragment lane
// layouts are identical on gfx950 (16x16x32: n=lane&15, k=(lane>>4)*8+j).
//  e 0..19 : phys phase-2 (16x16x32), e=(kk*2+Ks)*2+ftile
//  e 20..23: encoder conv (32x32x16), e-20=enc*2+mt; j<9 W, j==15 bias
//  e 24..25: phys phase-1 (32x32x16), mt=e-24;       j<15 W, j==15 bias
//  e 26..41: head stage-A [Ws|Wd] concat, K=64 N=64(o<60 valid):
//            e = 26 + side*8 + Kc*4 + ntile   (side 0=v, 1=p)
//  e 42..43: head Wsp, K=32 (k<30 W, k31 bsp), N=32 (o<30): e = 42+ntile
//  e 44..55: head Wa,  K=32 (k<30 W, k31 ba),  N=192:       e = 44+ntile
// ---------------------------------------------------------------------------
__global__ void prep_frags(const float* __restrict__ W2,
                           const float* __restrict__ Wc_v,
                           const float* __restrict__ Wc_p,
                           const float* __restrict__ W1,
                           const float* __restrict__ bc_v,
                           const float* __restrict__ bc_p,
                           const float* __restrict__ b1,
                           const float* __restrict__ Ws_v,
                           const float* __restrict__ Wd_v,
                           const float* __restrict__ Ws_p,
                           const float* __restrict__ Wd_p,
                           const float* __restrict__ Wsp,
                           const float* __restrict__ bsp,
                           const float* __restrict__ Wa,
                           const float* __restrict__ ba,
                           unsigned short* __restrict__ ws_frag)
{
    int gid = blockIdx.x * 256 + threadIdx.x;
    if (gid >= 56 * 64) return;
    int lane = gid & 63, e = gid >> 6;
    unsigned int w[4];
    if (e < 20) {
        int ft = e & 1, Ks = (e >> 1) & 1, kk = e >> 2;
        int m = lane & 15, kg = lane >> 4;
        int f = ft * 16 + m;
        #pragma unroll
        for (int p = 0; p < 4; ++p) {
            int i0 = Ks * 32 + kg * 8 + 2 * p;
            float v0 = (f < 30) ? W2[f * 320 + i0 * 5 + kk] : 0.f;
            float v1 = (f < 30) ? W2[f * 320 + (i0 + 1) * 5 + kk] : 0.f;
            w[p] = pk2(v0, v1);
        }
    } else if (e < 24) {
        int e2 = e - 20, enc = e2 >> 1, mt = e2 & 1;
        const float* Wc = enc ? Wc_p : Wc_v;
        const float* bc = enc ? bc_p : bc_v;
        int c = mt * 32 + (lane & 31), kg = lane >> 5;
        #pragma unroll
        for (int p = 0; p < 4; ++p) {
            int j0 = kg * 8 + 2 * p, j1 = j0 + 1;
            float v0 = (j0 < 9) ? Wc[c * 9 + (j0 % 3) * 3 + (j0 / 3)] : 0.f;
            float v1 = (j1 < 9) ? Wc[c * 9 + (j1 % 3) * 3 + (j1 / 3)]
                                : (j1 == 15 ? bc[c] : 0.f);
            w[p] = pk2(v0, v1);
        }
    } else if (e < 26) {
        int mt = e - 24;
        int c = mt * 32 + (lane & 31), kg = lane >> 5;
        #pragma unroll
        for (int p = 0; p < 4; ++p) {
            int j0 = kg * 8 + 2 * p, j1 = j0 + 1;
            float v0 = (j0 < 15) ? W1[c * 15 + (j0 % 3) * 5 + (j0 / 3)] : 0.f;
            float v1 = (j1 < 15) ? W1[c * 15 + (j1 % 3) * 5 + (j1 / 3)]
                                 : (j1 == 15 ? b1[c] : 0.f);
            w[p] = pk2(v0, v1);
        }
    } else if (e < 42) {
        int e2 = e - 26;
        int side = e2 >> 3, idx = e2 & 7;
        int Kc = idx >> 2, nt = idx & 3;
        const float* Ws = side ? Ws_p : Ws_v;
        const float* Wd = side ? Wd_p : Wd_v;
        int o = nt * 16 + (lane & 15), kg = lane >> 4;
        #pragma unroll
        for (int p = 0; p < 4; ++p) {
            int j0 = Kc * 32 + kg * 8 + 2 * p, j1 = j0 + 1;
            float v0 = (o < 30) ? Ws[j0 * 30 + o] : (o < 60 ? Wd[j0 * 30 + o - 30] : 0.f);
            float v1 = (o < 30) ? Ws[j1 * 30 + o] : (o < 60 ? Wd[j1 * 30 + o - 30] : 0.f);
            w[p] = pk2(v0, v1);
        }
    } else if (e < 44) {
        int nt = e - 42;
        int o = nt * 16 + (lane & 15), kg = lane >> 4;
        #pragma unroll
        for (int p = 0; p < 4; ++p) {
            int j0 = kg * 8 + 2 * p, j1 = j0 + 1;
            float v0 = 0.f, v1 = 0.f;
            if (o < 30) {
                v0 = (j0 < 30) ? Wsp[j0 * 30 + o] : (j0 == 31 ? bsp[o] : 0.f);
                v1 = (j1 < 30) ? Wsp[j1 * 30 + o] : (j1 == 31 ? bsp[o] : 0.f);
            }
            w[p] = pk2(v0, v1);
        }
    } else {
        int nt = e - 44;
        int c = nt * 16 + (lane & 15), kg = lane >> 4;
        #pragma unroll
        for (int p = 0; p < 4; ++p) {
            int j0 = kg * 8 + 2 * p, j1 = j0 + 1;
            float v0 = (j0 < 30) ? Wa[j0 * 192 + c] : (j0 == 31 ? ba[c] : 0.f);
            float v1 = (j1 < 30) ? Wa[j1 * 192 + c] : (j1 == 31 ? ba[c] : 0.f);
            w[p] = pk2(v0, v1);
        }
    }
    ((uint4*)ws_frag)[gid] = make_uint4(w[0], w[1], w[2], w[3]);
}

// ---------------------------------------------------------------------------
// MERGED encode + phys. grid = 3*B_, type = bx%3 (0: enc S_V, 1: enc S_P,
// 2: phys S_P1). ISSUE-BOUND fixes this round:
//  - persistent zero-C f32x16 hoisted out of both MFMA loops; launch_bounds
//    (512,4) gives 128 VGPR so the compiler keeps it + separate D regs
//    (at (512,6)/40-VGPR it re-zeroed 16 regs before EVERY mfma = 32 movs/iter)
//  - encoder epilogue: direct f32 relu-accumulate into 16-wide accumulators
//    (removes 16 pk2 + 4 sum-MFMAs per iter; also removes bf16 relu rounding)
// ---------------------------------------------------------------------------
#define P1TS 72
__global__ __launch_bounds__(512, 4) void enc_phys_kernel(
    const float* __restrict__ S_V, const float* __restrict__ S_P,
    const float* __restrict__ S_P1,
    const unsigned short* __restrict__ Frag,
    const float* __restrict__ b2,
    float* __restrict__ hv, float* __restrict__ hp, float* __restrict__ y30)
{
    __shared__ __align__(16) char smraw[12416 + 37440 + 1024];   // 50.9 KB
    float* sig = (float*)smraw;                                  // [3104]
    unsigned short* p1T = (unsigned short*)(smraw + 12416);      // phys [260*72]
    float* part = (float*)(smraw + 12416 + 37440);               // phys [8][32]
    float* red  = (float*)(smraw + 12416);                       // enc overlay [2][8][64]
    float* ymat = (float*)p1T;                                   // phys epilogue overlay

    const int bx = blockIdx.x;
    const int type = bx % 3;          // 0,1: encoder; 2: phys
    const int b = bx / 3;
    const int tid = threadIdx.x;
    const int lane = tid & 63, wv = tid >> 6;                    // wv 0..7
    const bf16x8* fr = (const bf16x8*)Frag;

    if (type < 2) {
        // =================== encoder path ===================
        const float* __restrict__ xb = (type ? S_P : S_V) + (size_t)b * 3072;
        float* hout = type ? hp : hv;
        const int n = lane & 31, kg = lane >> 5;

        #pragma unroll
        for (int i = 0; i < 3; ++i) {
            int idx = tid + i * 512;
            ((float2*)sig)[idx] = ((const float2*)xb)[idx];
        }
        bf16x8 Bf0 = fr[(20 + type * 2) * 64 + lane];   // weights ch 0..31
        bf16x8 Bf1 = fr[(21 + type * 2) * 64 + lane];   // weights ch 32..63
        __syncthreads();

        const f32x16 z = zero16();          // persistent zero-C bank
        float s0[16], s1[16];
        #pragma unroll
        for (int r = 0; r < 16; ++r) { s0[r] = 0.f; s1[r] = 0.f; }

        #pragma unroll 1
        for (int nt = wv; nt < 32; nt += 8) {
            const int t = nt * 32 + n;                 // n = time row of A
            union { unsigned int u[4]; bf16x8 v; } bb;
            bb.u[0] = bb.u[1] = bb.u[2] = bb.u[3] = 0u;
            if (t < 1022) {
                const float* xp = sig + 3 * t;
                if (kg == 0) {          // k=0..7 -> x[3t..3t+7]
                    bb.u[0] = pk2(xp[0], xp[1]); bb.u[1] = pk2(xp[2], xp[3]);
                    bb.u[2] = pk2(xp[4], xp[5]); bb.u[3] = pk2(xp[6], xp[7]);
                } else {                // k=8 -> x[3t+8]; k=15 -> 1.0 (bias col)
                    bb.u[0] = pk2(xp[8], 0.f);
                    bb.u[3] = 0x3F800000u;   // packed (0.0, 1.0) in bf16
                }
            }
            f32x16 y = __builtin_amdgcn_mfma_f32_32x32x16_bf16(bb.v, Bf0, z, 0, 0, 0);
            #pragma unroll
            for (int r = 0; r < 16; ++r) s0[r] += fmaxf(y[r], 0.f);
            y = __builtin_amdgcn_mfma_f32_32x32x16_bf16(bb.v, Bf1, z, 0, 0, 0);
            #pragma unroll
            for (int r = 0; r < 16; ++r) s1[r] += fmaxf(y[r], 0.f);
        }

        // lane-local tree sums (16 -> 1), then cross-wave reduce (R4 layout)
        float t0, t1;
        {
            float a0 = (s0[0]+s0[1]) + (s0[2]+s0[3]);
            float a1 = (s0[4]+s0[5]) + (s0[6]+s0[7]);
            float a2 = (s0[8]+s0[9]) + (s0[10]+s0[11]);
            float a3 = (s0[12]+s0[13]) + (s0[14]+s0[15]);
            t0 = (a0 + a1) + (a2 + a3);
            float c0 = (s1[0]+s1[1]) + (s1[2]+s1[3]);
            float c1 = (s1[4]+s1[5]) + (s1[6]+s1[7]);
            float c2 = (s1[8]+s1[9]) + (s1[10]+s1[11]);
            float c3 = (s1[12]+s1[13]) + (s1[14]+s1[15]);
            t1 = (c0 + c1) + (c2 + c3);
        }
        __syncthreads();                 // sig reads done; red overlays p1T region
        red[(0 * 8 + wv) * 64 + lane] = t0;
        red[(1 * 8 + wv) * 64 + lane] = t1;
        __syncthreads();
        if (tid < 64) {                  // tid = channel c
            int half = tid >> 5, c32 = tid & 31;
            float s = 0.f;
            #pragma unroll
            for (int w = 0; w < 8; ++w)
                s += red[(half * 8 + w) * 64 + c32] + red[(half * 8 + w) * 64 + c32 + 32];
            hout[(size_t)b * 64 + tid] = s * (1.0f / 1022.0f);
        }
        return;
    }

    // =================== phys path ===================
    const float* __restrict__ xb = S_P1 + (size_t)b * 3072;

    #pragma unroll
    for (int i = 0; i < 3; ++i) {
        int idx = tid + i * 512;
        ((float2*)sig)[idx] = ((const float2*)xb)[idx];
    }
    if (tid < 16) ((float2*)sig)[1536 + tid] = make_float2(0.f, 0.f);
    if (tid < 180) ((unsigned int*)(p1T + 255 * P1TS))[tid] = 0u;
    __syncthreads();

    // ---- phase 1 ----
    {
        const int n = lane & 31, kg2 = lane >> 5;
        bf16x8 W10 = fr[24 * 64 + lane];
        bf16x8 W11 = fr[25 * 64 + lane];
        const f32x16 z = zero16();      // persistent zero-C bank
        #pragma unroll 1
        for (int ntl = wv; ntl < 32; ntl += 8) {
            const int t = ntl * 32 + n;
            const float* xp = sig + 3 * t + kg2 * 8;
            union { unsigned int u[4]; bf16x8 v; } bb;
            bb.u[0] = pk2(xp[0], xp[1]);
            bb.u[1] = pk2(xp[2], xp[3]);
            bb.u[2] = pk2(xp[4], xp[5]);
            bb.u[3] = pk2(xp[6], kg2 ? 1.0f : xp[7]);
            f32x16 y = __builtin_amdgcn_mfma_f32_32x32x16_bf16(bb.v, W10, z, 0, 0, 0);
            #pragma unroll
            for (int g4 = 0; g4 < 4; ++g4) {
                const int t4 = ntl * 8 + 2 * g4 + kg2;
                if (t4 < 255) {
                    float p0 = max4(y[4*g4+0], y[4*g4+1], y[4*g4+2], y[4*g4+3]);
                    p1T[t4 * P1TS + n] = (unsigned short)pk2(p0, p0);
                }
            }
            y = __builtin_amdgcn_mfma_f32_32x32x16_bf16(bb.v, W11, z, 0, 0, 0);
            #pragma unroll
            for (int g4 = 0; g4 < 4; ++g4) {
                const int t4 = ntl * 8 + 2 * g4 + kg2;
                if (t4 < 255) {
                    float p1 = max4(y[4*g4+0], y[4*g4+1], y[4*g4+2], y[4*g4+3]);
                    p1T[t4 * P1TS + n + 32] = (unsigned short)pk2(p1, p1);
                }
            }
        }
    }
    __syncthreads();

    // ---- phase 2 ----
    const int m_ = lane & 15, kg16 = lane >> 4;
    f32x4 acc[2][2];
    #pragma unroll
    for (int q = 0; q < 2; ++q) {
        acc[q][0] = (f32x4){0.f, 0.f, 0.f, 0.f};
        acc[q][1] = (f32x4){0.f, 0.f, 0.f, 0.f};
    }
    #pragma unroll 1
    for (int Ks = 0; Ks < 2; ++Ks) {
        bf16x8 Wf[10];
        #pragma unroll
        for (int kk = 0; kk < 5; ++kk) {
            Wf[kk * 2]     = fr[((kk * 2 + Ks) * 2) * 64 + lane];
            Wf[kk * 2 + 1] = fr[((kk * 2 + Ks) * 2 + 1) * 64 + lane];
        }
        #pragma unroll
        for (int kk = 0; kk < 5; ++kk) {
            #pragma unroll
            for (int q = 0; q < 2; ++q) {
                const int row = wv * 32 + q * 16 + m_ + kk;
                const bf16x8 Pf = *(const bf16x8*)(p1T + row * P1TS + Ks * 32 + kg16 * 8);
                acc[q][0] = __builtin_amdgcn_mfma_f32_16x16x32_bf16(Pf, Wf[kk*2],   acc[q][0], 0, 0, 0);
                acc[q][1] = __builtin_amdgcn_mfma_f32_16x16x32_bf16(Pf, Wf[kk*2+1], acc[q][1], 0, 0, 0);
            }
        }
    }
    __syncthreads();

    #pragma unroll
    for (int q = 0; q < 2; ++q) {
        #pragma unroll
        for (int ft = 0; ft < 2; ++ft) {
            f32x4 av = acc[q][ft];
            float p = max4(av[0], av[1], av[2], av[3]);
            int n4 = wv * 8 + q * 4 + kg16;
            ymat[n4 * 36 + ft * 16 + m_] = p;
        }
    }
    __syncthreads();
    if (tid < 256) {
        int w8 = tid >> 5, f = tid & 31;
        if (f < 30) {
            float s = 0.f;
            #pragma unroll 2
            for (int r = w8; r < 62; r += 8) s += ymat[r * 36 + f];
            part[w8 * 32 + f] = s;
        }
    }
    __syncthreads();
    if (tid < 30) {
        float s = 0.f;
        #pragma unroll
        for (int w8 = 0; w8 < 8; ++w8) s += part[w8 * 32 + tid];
        y30[(size_t)b * 30 + tid] = s * (1.0f / 62.0f) + b2[tid];
    }
}

// ---------------------------------------------------------------------------
// Head as batched MFMA GEMMs (unchanged from R6 — verified).
// ---------------------------------------------------------------------------
__global__ __launch_bounds__(256, 2) void head_kernel(
    const int* __restrict__ pairs,
    const float* __restrict__ hv_g, const float* __restrict__ hp_g,
    const float* __restrict__ y30_g,
    const unsigned short* __restrict__ Frag,
    const float* __restrict__ bs_v, const float* __restrict__ bd_v,
    const float* __restrict__ bs_p, const float* __restrict__ bd_p,
    const float* __restrict__ Wf,  const float* __restrict__ bf,
    float* __restrict__ out)
{
    __shared__ __align__(16) float vs_tmp[16][36], ps_tmp[16][36];
    __shared__ __align__(16) float h1l[16][36], h2l[16][36];
    __shared__ __align__(16) float tok[4][16][36];
    __shared__ __align__(16) float qkl[4 * 3144];      // t*3144 + s*196 + c
    __shared__ __align__(16) float qml[16][32];
    __shared__ float wsml[16][4][4];
    __shared__ int pfl[16];
    const int b0 = blockIdx.x * HB;
    const int tid = threadIdx.x, lane = tid & 63, wv = tid >> 6;
    const bf16x8* fr = (const bf16x8*)Frag;
    const int sA = lane & 15, kgA = lane >> 4;
    union U { unsigned int u[4]; bf16x8 v; };

    if (tid < 16) {
        pfl[tid] = pairs[b0 + tid];
        vs_tmp[tid][30] = 0.f; vs_tmp[tid][31] = 1.0f;
        ps_tmp[tid][30] = 0.f; ps_tmp[tid][31] = 1.0f;
        #pragma unroll
        for (int t = 0; t < 4; ++t) { tok[t][tid][30] = 0.f; tok[t][tid][31] = 1.0f; }
    }
    #pragma unroll
    for (int i = 0; i < 2; ++i) {
        int idx = tid + i * 256;
        int s = idx >> 5, o = idx & 31;
        if (o < 30) tok[2][s][o] = y30_g[(size_t)(b0 + s) * 30 + o];
    }

    // ---- stage A ----
    U Av0, Av1, Ap0, Ap1;
    {
        const float* hvp = hv_g + (size_t)(b0 + sA) * 64 + kgA * 8;
        const float* hpp = hp_g + (size_t)(b0 + sA) * 64 + kgA * 8;
        float4 x0 = *(const float4*)(hvp),      x1 = *(const float4*)(hvp + 4);
        float4 x2 = *(const float4*)(hvp + 32), x3 = *(const float4*)(hvp + 36);
        Av0.u[0] = pk2(x0.x, x0.y); Av0.u[1] = pk2(x0.z, x0.w);
        Av0.u[2] = pk2(x1.x, x1.y); Av0.u[3] = pk2(x1.z, x1.w);
        Av1.u[0] = pk2(x2.x, x2.y); Av1.u[1] = pk2(x2.z, x2.w);
        Av1.u[2] = pk2(x3.x, x3.y); Av1.u[3] = pk2(x3.z, x3.w);
        float4 y0 = *(const float4*)(hpp),      y1 = *(const float4*)(hpp + 4);
        float4 y2 = *(const float4*)(hpp + 32), y3 = *(const float4*)(hpp + 36);
        Ap0.u[0] = pk2(y0.x, y0.y); Ap0.u[1] = pk2(y0.z, y0.w);
        Ap0.u[2] = pk2(y1.x, y1.y); Ap0.u[3] = pk2(y1.z, y1.w);
        Ap1.u[0] = pk2(y2.x, y2.y); Ap1.u[1] = pk2(y2.z, y2.w);
        Ap1.u[2] = pk2(y3.x, y3.y); Ap1.u[3] = pk2(y3.z, y3.w);
    }
    {
        f32x4 accv = (f32x4){0.f,0.f,0.f,0.f}, accp = (f32x4){0.f,0.f,0.f,0.f};
        accv = __builtin_amdgcn_mfma_f32_16x16x32_bf16(Av0.v, fr[(26 + wv) * 64 + lane], accv, 0, 0, 0);
        accv = __builtin_amdgcn_mfma_f32_16x16x32_bf16(Av1.v, fr[(30 + wv) * 64 + lane], accv, 0, 0, 0);
        accp = __builtin_amdgcn_mfma_f32_16x16x32_bf16(Ap0.v, fr[(34 + wv) * 64 + lane], accp, 0, 0, 0);
        accp = __builtin_amdgcn_mfma_f32_16x16x32_bf16(Ap1.v, fr[(38 + wv) * 64 + lane], accp, 0, 0, 0);
        int oD = wv * 16 + sA;
        bool lo = oD < 30, hi = (oD >= 30) && (oD < 60);
        float bv = 0.f, bp = 0.f;
        if (lo) { bv = bs_v[oD]; bp = bs_p[oD]; }
        else if (hi) { bv = bd_v[oD - 30]; bp = bd_p[oD - 30]; }
        #pragma unroll
        for (int r = 0; r < 4; ++r) {
            int s = kgA * 4 + r;
            if (lo)      { vs_tmp[s][oD] = accv[r] + bv;  ps_tmp[s][oD] = accp[r] + bp; }
            else if (hi) { tok[3][s][oD-30] = accv[r] + bv; tok[0][s][oD-30] = accp[r] + bp; }
        }
    }
    __syncthreads();

    // ---- stage B ----
    {
        int side = wv >> 1, nt = wv & 1;
        const float (*src)[36] = side ? ps_tmp : vs_tmp;
        const float* ap = &src[sA][kgA * 8];
        float4 x0 = *(const float4*)ap, x1 = *(const float4*)(ap + 4);
        U A;
        A.u[0] = pk2(x0.x, x0.y); A.u[1] = pk2(x0.z, x0.w);
        A.u[2] = pk2(x1.x, x1.y); A.u[3] = pk2(x1.z, x1.w);
        f32x4 acc = (f32x4){0.f,0.f,0.f,0.f};
        acc = __builtin_amdgcn_mfma_f32_16x16x32_bf16(A.v, fr[(42 + nt) * 64 + lane], acc, 0, 0, 0);
        int oD = nt * 16 + sA;
        if (oD < 30) {
            float (*dst)[36] = side ? h2l : h1l;
            #pragma unroll
            for (int r = 0; r < 4; ++r) dst[kgA * 4 + r][oD] = acc[r];
        }
    }
    __syncthreads();

    // ---- LSE soft-OR fusion -> tok[1] ----
    #pragma unroll
    for (int i = 0; i < 2; ++i) {
        int idx = tid + i * 256;
        int s = idx >> 5, o = idx & 31;
        if (o < 30) {
            float h1 = h1l[s][o], h2 = h2l[s][o], h12 = h1 + h2;
            float m1 = fmaxf(h12, fmaxf(h1, h2));
            float lse1 = m1 + logf(2.f*expf(h12 - m1) + expf(h1 - m1) + expf(h2 - m1));
            float m2 = fmaxf(0.f, fmaxf(h1, h2));
            float lse2 = m2 + logf(2.f*expf(-m2) + expf(h1 - m2) + expf(h2 - m2));
            tok[1][s][o] = pfl[s] ? (lse1 - lse2) : h2;
        }
    }
    __syncthreads();

    // ---- stage C ----
    {
        const float* ap = &tok[wv][sA][kgA * 8];
        float4 x0 = *(const float4*)ap, x1 = *(const float4*)(ap + 4);
        U A;
        A.u[0] = pk2(x0.x, x0.y); A.u[1] = pk2(x0.z, x0.w);
        A.u[2] = pk2(x1.x, x1.y); A.u[3] = pk2(x1.z, x1.w);
        #pragma unroll
        for (int nt = 0; nt < 12; ++nt) {
            f32x4 acc = (f32x4){0.f,0.f,0.f,0.f};
            acc = __builtin_amdgcn_mfma_f32_16x16x32_bf16(A.v, fr[(44 + nt) * 64 + lane], acc, 0, 0, 0);
            int c = nt * 16 + sA;
            #pragma unroll
            for (int r = 0; r < 4; ++r)
                qkl[wv * 3144 + (kgA * 4 + r) * 196 + c] = acc[r];
        }
    }
    __syncthreads();

    // ---- stage D ----
    #pragma unroll
    for (int i = 0; i < 2; ++i) {
        int idx = tid + i * 256;
        int s = idx >> 5, d = idx & 31;
        float q0 = qkl[0*3144 + s*196 + d], q1 = qkl[1*3144 + s*196 + d];
        float q2 = qkl[2*3144 + s*196 + d], q3 = qkl[3*3144 + s*196 + d];
        qml[s][d] = pfl[s] ? (q0 + q1 + q2 + q3) * 0.25f
                           : (q0 + q1 + q2) * (1.f / 3.f);
    }
    __syncthreads();
    {
        int s = tid >> 4, n = (tid >> 2) & 3, t = tid & 3;
        const float4* kp = (const float4*)&qkl[t*3144 + s*196 + 64 + 32*n];
        const float4* qp = (const float4*)&qml[s][0];
        float a = 0.f;
        #pragma unroll
        for (int d4 = 0; d4 < 8; ++d4) {
            float4 k4 = kp[d4], q4 = qp[d4];
            a += k4.x*q4.x + k4.y*q4.y + k4.z*q4.z + k4.w*q4.w;
        }
        a *= 0.17677669529663687f;
        if (t == 3 && pfl[s] == 0) a = -INFINITY;
        float m = maxq(a);
        float e = expf(a - m);
        float ssum = sumq(e);
        wsml[s][n][t] = e / ssum;
    }
    __syncthreads();
    if (tid < 64) {
        int s = tid >> 2, n = tid & 3;
        float w0 = wsml[s][n][0], w1 = wsml[s][n][1];
        float w2 = wsml[s][n][2], w3 = wsml[s][n][3];
        const float4* v0 = (const float4*)&qkl[0*3144 + s*196 + 32];
        const float4* v1 = (const float4*)&qkl[1*3144 + s*196 + 32];
        const float4* v2 = (const float4*)&qkl[2*3144 + s*196 + 32];
        const float4* v3 = (const float4*)&qkl[3*3144 + s*196 + 32];
        float acc = bf[n];
        #pragma unroll
        for (int d4 = 0; d4 < 8; ++d4) {
            float4 a0 = v0[d4], a1 = v1[d4], a2 = v2[d4], a3 = v3[d4];
            int d = d4 * 4;
            float f0 = w0*a0.x + w1*a1.x + w2*a2.x + w3*a3.x;
            float f1 = w0*a0.y + w1*a1.y + w2*a2.y + w3*a3.y;
            float f2 = w0*a0.z + w1*a1.z + w2*a2.z + w3*a3.z;
            float f3 = w0*a0.w + w1*a1.w + w2*a2.w + w3*a3.w;
            acc += f0 * Wf[d*4 + n]     + f1 * Wf[(d+1)*4 + n]
                 + f2 * Wf[(d+2)*4 + n] + f3 * Wf[(d+3)*4 + n];
        }
        out[(size_t)(b0 + s) * 4 + n] = acc;
    }
}

// ---------------------------------------------------------------------------
extern "C" void kernel_launch(void* const* d_in, const int* in_sizes, int n_in,
                              void* d_out, int out_size, void* d_ws, size_t ws_size,
                              hipStream_t stream)
{
    const int*   pairs = (const int*)  d_in[0];
    const float* S_V   = (const float*)d_in[1];
    const float* S_P   = (const float*)d_in[2];
    const float* S_P1  = (const float*)d_in[3];
    const float* Wc_v  = (const float*)d_in[4];
    const float* bc_v  = (const float*)d_in[5];
    const float* Ws_v  = (const float*)d_in[6];
    const float* bs_v  = (const float*)d_in[7];
    const float* Wd_v  = (const float*)d_in[8];
    const float* bd_v  = (const float*)d_in[9];
    const float* Wc_p  = (const float*)d_in[10];
    const float* bc_p  = (const float*)d_in[11];
    const float* Ws_p  = (const float*)d_in[12];
    const float* bs_p  = (const float*)d_in[13];
    const float* Wd_p  = (const float*)d_in[14];
    const float* bd_p  = (const float*)d_in[15];
    const float* Wsp   = (const float*)d_in[16];
    const float* bsp   = (const float*)d_in[17];
    const float* W1    = (const float*)d_in[18];
    const float* b1    = (const float*)d_in[19];
    const float* W2    = (const float*)d_in[20];
    const float* b2    = (const float*)d_in[21];
    const float* Wa    = (const float*)d_in[22];
    const float* ba    = (const float*)d_in[23];
    const float* Wf    = (const float*)d_in[24];
    const float* bf    = (const float*)d_in[25];
    float* out = (float*)d_out;

    // ws: h_v[B][64] | h_p[B][64] | y30[B][30] | frags (56 x 64 x 16B)
    float* ws  = (float*)d_ws;
    float* h_v = ws;
    float* h_p = ws + (size_t)B_ * 64;
    float* y30 = ws + (size_t)2 * B_ * 64;
    unsigned short* Frag = (unsigned short*)(ws + (size_t)2 * B_ * 64 + (size_t)B_ * 30);

    prep_frags<<<14, 256, 0, stream>>>(W2, Wc_v, Wc_p, W1, bc_v, bc_p, b1,
                                       Ws_v, Wd_v, Ws_p, Wd_p, Wsp, bsp, Wa, ba,
                                       Frag);
    enc_phys_kernel<<<3 * B_, 512, 0, stream>>>(
        S_V, S_P, S_P1, Frag, b2, h_v, h_p, y30);
    head_kernel<<<B_ / HB, 256, 0, stream>>>(
        pairs, h_v, h_p, y30, Frag,
        bs_v, bd_v, bs_p, bd_p, Wf, bf, out);
}